// Round 1
// baseline (225.509 us; speedup 1.0000x reference)
//
#include <hip/hip_runtime.h>
#include <hip/hip_bf16.h>
#include <cstdint>
#include <cmath>

#define AS1 __attribute__((address_space(1)))
#define AS3 __attribute__((address_space(3)))

typedef unsigned short u16;
typedef uint32_t u32;
typedef __attribute__((ext_vector_type(8))) __bf16 bf16x8;
typedef __attribute__((ext_vector_type(8))) unsigned short u16x8;
typedef __attribute__((ext_vector_type(4))) float f32x4;

// fp32 -> bf16 round-to-nearest-even
__device__ __forceinline__ u16 f2bf(float f) {
    uint32_t u = __builtin_bit_cast(uint32_t, f);
    return (u16)((u + 0x7fffu + ((u >> 16) & 1u)) >> 16);
}

// order-preserving float -> u32 map (for integer atomicMax); 0 is below all reals
__device__ __forceinline__ u32 f2ord(float f) {
    u32 u = __builtin_bit_cast(u32, f);
    return u ^ (u32)(((int32_t)u >> 31) | 0x80000000);
}
__device__ __forceinline__ float ord2f(u32 v) {
    u32 u = (v & 0x80000000u) ? (v ^ 0x80000000u) : ~v;
    return __builtin_bit_cast(float, u);
}

// ---------------- fused setup (control, = r13) ----------------
// ALGEBRA: relu(h)=(h+|h|)/2, relu(-h)=(|h|-h)/2  =>
//   leaf = |h| @ Ws^T + x @ Wc^T + cl
__global__ void setup_all(const float* __restrict__ x,
                          const float* __restrict__ Wd, const float* __restrict__ bd,
                          const float* __restrict__ Wa, const float* __restrict__ ba,
                          const float* __restrict__ Wl,
                          u16* __restrict__ xb, u16* __restrict__ w1b,
                          float* __restrict__ bb, u16* __restrict__ w1t,
                          u16* __restrict__ wsb, u16* __restrict__ dlb,
                          float* __restrict__ cl) {
    __shared__ float cred[256];
    const int b = blockIdx.x;
    const int tid = threadIdx.x;
    if (b < 2048) {
        long idx = (long)(b * 256 + tid) * 8;
        float4 a = *(const float4*)(x + idx);
        float4 c = *(const float4*)(x + idx + 4);
        u16x8 o;
        o[0]=f2bf(a.x); o[1]=f2bf(a.y); o[2]=f2bf(a.z); o[3]=f2bf(a.w);
        o[4]=f2bf(c.x); o[5]=f2bf(c.y); o[6]=f2bf(c.z); o[7]=f2bf(c.w);
        *(u16x8*)(xb + idx) = o;
    } else if (b < 2112) {
        int t = (b - 2048) * 256 + tid;   // 16384 threads
        int row = t >> 4, g = (t & 15) * 8;
        const float* src = nullptr;
        if (row < 511)       src = Wd + row * 128 + g;
        else if (row < 1023) src = Wa + (row - 511) * 128 + g;
        u16x8 o = 0;
        if (src) {
            #pragma unroll
            for (int j = 0; j < 8; ++j) o[j] = f2bf(src[j]);
        }
        *(u16x8*)(w1b + row * 128 + g) = o;
        #pragma unroll
        for (int j = 0; j < 8; ++j) w1t[(g + j) * 1024 + row] = o[j];
        if ((t & 15) == 0)
            bb[row] = row < 511 ? bd[row] : (row < 1023 ? ba[row - 511] : 0.f);
    } else {
        const int l0 = (b - 2112) * 2;
        const int lo = tid >> 7, g = (tid & 127) * 8;
        const float* src = Wl + (long)(l0 + lo) * 2046;
        u16x8 os, od;
        float part = 0.f;
        #pragma unroll
        for (int j = 0; j < 8; ++j) {
            int c = g + j;
            float pa = 0.f, pb = 0.f;
            if (c < 1023) { pa = src[c]; pb = src[1023 + c]; }
            os[j] = f2bf(0.5f * (pa + pb));
            float v = pa - pb;
            od[j] = f2bf(v);
            float b1 = c < 511 ? bd[c] : (c < 1023 ? ba[c - 511] : 0.f);
            part += v * b1;
        }
        *(u16x8*)(wsb + (long)(l0 + lo) * 1024 + g) = os;
        *(u16x8*)(dlb + (long)(l0 + lo) * 1024 + g) = od;
        cred[tid] = part;
        __syncthreads();
        if (tid < 2) {
            float s = 0.f;
            #pragma unroll
            for (int k = 0; k < 128; ++k) s += cred[tid * 128 + k];
            cl[l0 + tid] = 0.5f * s;
        }
    }
}

// ---------------- gemm_hwc: fused habs-GEMM + Wc-GEMM (unchanged from r14) --------
__global__ __launch_bounds__(256) void gemm_hwc(
        const u16* __restrict__ xb, const u16* __restrict__ w1b,
        const float* __restrict__ bb,
        const u16* __restrict__ dlb, const u16* __restrict__ w1t,
        u16* __restrict__ habs, u16* __restrict__ wcb) {
    __shared__ union SharedU {
        struct { u16 As[2][4096]; u16 Bs[2][4096]; } s;  // 32 KB, 2 K-panels of 32
        u16 obuf[128 * 132];                             // 33.8 KB epilogue overlay
    } sh;
    const int tid  = threadIdx.x;
    const int lane = tid & 63, wave = tid >> 6;
    const int wy = wave >> 1, wx = wave & 1;
    const int i16 = lane & 15, q = lane >> 4;
    const int cA = wave * 2, srow = lane >> 2, scol = (lane & 3) * 8;

    f32x4 acc[4][4];
    #pragma unroll
    for (int m = 0; m < 4; ++m)
        #pragma unroll
        for (int n = 0; n < 4; ++n) acc[m][n] = f32x4{0.f,0.f,0.f,0.f};

    if (blockIdx.y == 0) {
        // ---- wc role: Wc = 0.5*dlb@w1t^T, K=1024, BK=32 in panel 0 ----
        const long blockM = (long)blockIdx.x * 128;
        const int koff = (blockIdx.x * 4) & 31;
        const u16* a0 = dlb + (blockM + cA * 16 + srow) * 1024 + scol;
        const u16* a1 = dlb + (blockM + (cA + 1) * 16 + srow) * 1024 + scol;
        const u16* b0 = w1t + (long)(cA * 16 + srow) * 1024 + scol;
        const u16* b1 = w1t + (long)((cA + 1) * 16 + srow) * 1024 + scol;
        for (int it = 0; it < 32; ++it) {
            const int k0 = ((it + koff) & 31) << 5;
            __builtin_amdgcn_global_load_lds((const AS1 void*)(a0 + k0), (AS3 void*)&sh.s.As[0][cA * 512],       16, 0, 0);
            __builtin_amdgcn_global_load_lds((const AS1 void*)(a1 + k0), (AS3 void*)&sh.s.As[0][(cA + 1) * 512], 16, 0, 0);
            __builtin_amdgcn_global_load_lds((const AS1 void*)(b0 + k0), (AS3 void*)&sh.s.Bs[0][cA * 512],       16, 0, 0);
            __builtin_amdgcn_global_load_lds((const AS1 void*)(b1 + k0), (AS3 void*)&sh.s.Bs[0][(cA + 1) * 512], 16, 0, 0);
            __syncthreads();
            bf16x8 af[4], bfv[4];
            #pragma unroll
            for (int s = 0; s < 4; ++s) {
                af[s]  = *(const bf16x8*)&sh.s.As[0][(wy * 64 + s * 16 + i16) * 32 + q * 8];
                bfv[s] = *(const bf16x8*)&sh.s.Bs[0][(wx * 64 + s * 16 + i16) * 32 + q * 8];
            }
            #pragma unroll
            for (int sm = 0; sm < 4; ++sm)
                #pragma unroll
                for (int sn = 0; sn < 4; ++sn)
                    acc[sm][sn] = __builtin_amdgcn_mfma_f32_16x16x32_bf16(af[sm], bfv[sn], acc[sm][sn], 0, 0, 0);
            __syncthreads();
        }
        #pragma unroll
        for (int sm = 0; sm < 4; ++sm)
            #pragma unroll
            for (int sn = 0; sn < 4; ++sn) {
                const int col = wx * 64 + sn * 16 + i16;     // 0..127
                #pragma unroll
                for (int r = 0; r < 4; ++r) {
                    const long row = blockM + wy * 64 + sm * 16 + 4 * q + r;
                    wcb[row * 128 + col] = f2bf(0.5f * acc[sm][sn][r]);
                }
            }
        return;
    }

    // ---- h role: habs = |xb @ w1b^T + bb|, BK=64 x 2 iters ----
    const int xcd = blockIdx.x, yy = blockIdx.y - 1;   // yy in 0..255
    const long blockM = (long)(xcd * 32 + (yy >> 3)) * 128;
    const int  blockN = (yy & 7) * 128;
    const int  koff = (yy >> 3) & 1;

    const u16* a0 = xb + (blockM + cA * 16 + srow) * 128 + scol;
    const u16* a1 = xb + (blockM + (cA + 1) * 16 + srow) * 128 + scol;
    const u16* b0 = w1b + ((long)blockN + cA * 16 + srow) * 128 + scol;
    const u16* b1 = w1b + ((long)blockN + (cA + 1) * 16 + srow) * 128 + scol;
    for (int it = 0; it < 2; ++it) {
        const int k0 = ((it + koff) & 1) << 6;
        #pragma unroll
        for (int p = 0; p < 2; ++p) {
            const int kp = k0 + p * 32;
            __builtin_amdgcn_global_load_lds((const AS1 void*)(a0 + kp), (AS3 void*)&sh.s.As[p][cA * 512],       16, 0, 0);
            __builtin_amdgcn_global_load_lds((const AS1 void*)(a1 + kp), (AS3 void*)&sh.s.As[p][(cA + 1) * 512], 16, 0, 0);
            __builtin_amdgcn_global_load_lds((const AS1 void*)(b0 + kp), (AS3 void*)&sh.s.Bs[p][cA * 512],       16, 0, 0);
            __builtin_amdgcn_global_load_lds((const AS1 void*)(b1 + kp), (AS3 void*)&sh.s.Bs[p][(cA + 1) * 512], 16, 0, 0);
        }
        __syncthreads();
        #pragma unroll
        for (int p = 0; p < 2; ++p) {
            bf16x8 af[4], bfv[4];
            #pragma unroll
            for (int s = 0; s < 4; ++s) {
                af[s]  = *(const bf16x8*)&sh.s.As[p][(wy * 64 + s * 16 + i16) * 32 + q * 8];
                bfv[s] = *(const bf16x8*)&sh.s.Bs[p][(wx * 64 + s * 16 + i16) * 32 + q * 8];
            }
            #pragma unroll
            for (int sm = 0; sm < 4; ++sm)
                #pragma unroll
                for (int sn = 0; sn < 4; ++sn)
                    acc[sm][sn] = __builtin_amdgcn_mfma_f32_16x16x32_bf16(af[sm], bfv[sn], acc[sm][sn], 0, 0, 0);
        }
        __syncthreads();   // also guards obuf overlay of As/Bs
    }

    float bv[4];
    #pragma unroll
    for (int sn = 0; sn < 4; ++sn) bv[sn] = bb[blockN + wx * 64 + sn * 16 + i16];
    #pragma unroll
    for (int sm = 0; sm < 4; ++sm)
        #pragma unroll
        for (int sn = 0; sn < 4; ++sn)
            #pragma unroll
            for (int r = 0; r < 4; ++r)
                sh.obuf[(wy * 64 + sm * 16 + 4 * q + r) * 132 + wx * 64 + sn * 16 + i16] =
                    f2bf(fabsf(acc[sm][sn][r] + bv[sn]));
    __syncthreads();
    const int cg = (tid & 15) * 8;
    #pragma unroll
    for (int it = 0; it < 8; ++it) {
        const int row = it * 16 + (tid >> 4);
        *(u16x8*)&habs[(blockM + row) * 1024 + blockN + cg] =
            *(const u16x8*)&sh.obuf[row * 132 + cg];
    }
}

// ---------------- GEMM2 (R15): 256^2-tile 8-wave 4-phase/K-tile pipelined ----------
// leaf = habs@Ws^T + xb@Wc^T + cl, fused ragged-max.
// K-tiles: t=0..15 habs(1024-stride)/wsb; t=16,17 xb(128-stride)/wcb.  NT=18.
// LDS panels As/Bs[slot=t&1][kk][256 rows][32 cols] (row stride 64B -> ds_read_b128
// chunk bits {q,row&1} = 8 chunks x 8 lanes = 2/bank = conflict-free, no swizzle).
// STAGE LEDGER (panel -> issue phase):  T.Akk0 <- (T-2).ph1 ; T.Bkk0 <- (T-2).ph2 ;
//   T.Akk1 <- (T-2).ph3 ; T.Bkk1 <- (T-1).ph0.   Every target region's last ds_read
//   completes (lgkmcnt0) before the barrier preceding the stage issue.
// GATES (end of ph1 & ph3, before closing barrier): steady vmcnt(10); tail: t=16 ->
//   8 / 4, t=17 -> 0 / none (skipped stages would make vmcnt(10) vacuous).
#define NT 18
__global__ __launch_bounds__(512, 2) void gemm_leaf(const u16* __restrict__ habs,
        const u16* __restrict__ xb, const u16* __restrict__ wsb,
        const u16* __restrict__ wcb, const float* __restrict__ cl,
        const int* __restrict__ seg, u32* __restrict__ pp) {
    __shared__ u16 As[2][2][256 * 32];   // 64 KB
    __shared__ u16 Bs[2][2][256 * 32];   // 64 KB
    __shared__ u32 pmax[256 * 17];       // 17 KB, stride 17 spreads atomic windows

    const int tid  = threadIdx.x;
    const int lane = tid & 63, w = tid >> 6;
    const int wm = w >> 2, wn = w & 3;            // 2x4 wave grid, wave tile 128x64
    const int i16 = lane & 15, q = lane >> 4;

    // XCD-aware swizzle over 512 blocks (512%8==0 -> bijective)
    const int bid  = blockIdx.x;
    const int wgid = (bid & 7) * 64 + (bid >> 3);
    const int mT = wgid >> 2, nT = wgid & 3;
    const long blockM = (long)mT * 256;
    const int  blockN = nT * 256;

    #pragma unroll
    for (int j = 0; j < 9; ++j) {
        int idx = tid + j * 512;
        if (idx < 256 * 17) pmax[idx] = 0u;       // below all reals
    }

    // staging: thread covers rows {tid>>2, 128+(tid>>2)}, colbytes (tid&3)*16 per panel
    const int r0 = tid >> 2, c0 = (tid & 3) * 8;
    const u16* gA1 = habs + (blockM + r0) * 1024 + c0;
    const u16* gB1 = wsb  + (long)(blockN + r0) * 1024 + c0;
    const u16* gA2 = xb   + (blockM + r0) * 128 + c0;
    const u16* gB2 = wcb  + (long)(blockN + r0) * 128 + c0;
    const int ldsb = w * 512;                     // wave-uniform LDS base (u16)

    auto stage = [&](int t, int isB, int kk) {    // one 16 KB panel = 2 loads/thread
        u16* dst = (isB ? &Bs[t & 1][kk][0] : &As[t & 1][kk][0]) + ldsb;
        const u16* g;
        int jstr;
        if (t < 16) { g = (isB ? gB1 : gA1) + t * 64 + kk * 32;        jstr = 128 * 1024; }
        else        { g = (isB ? gB2 : gA2) + (t - 16) * 64 + kk * 32; jstr = 128 * 128; }
        __builtin_amdgcn_global_load_lds((const AS1 void*)g,          (AS3 void*)dst,          16, 0, 0);
        __builtin_amdgcn_global_load_lds((const AS1 void*)(g + jstr), (AS3 void*)(dst + 4096), 16, 0, 0);
    };

    f32x4 acc[8][4];
    #pragma unroll
    for (int m = 0; m < 8; ++m)
        #pragma unroll
        for (int n = 0; n < 4; ++n) acc[m][n] = f32x4{0.f,0.f,0.f,0.f};
    bf16x8 areg[8], breg[2];

    auto lda = [&](int slot, int kk) {
        #pragma unroll
        for (int mf = 0; mf < 8; ++mf)
            areg[mf] = *(const bf16x8*)&As[slot][kk][(wm * 128 + mf * 16 + i16) * 32 + q * 8];
    };
    auto ldb = [&](int slot, int kk, int nh) {
        #pragma unroll
        for (int nf = 0; nf < 2; ++nf)
            breg[nf] = *(const bf16x8*)&Bs[slot][kk][(wn * 64 + nh * 32 + nf * 16 + i16) * 32 + q * 8];
    };
    auto mfma16 = [&](int nh) {
        #pragma unroll
        for (int mf = 0; mf < 8; ++mf)
            #pragma unroll
            for (int nf = 0; nf < 2; ++nf)
                acc[mf][nh * 2 + nf] = __builtin_amdgcn_mfma_f32_16x16x32_bf16(
                    areg[mf], breg[nf], acc[mf][nh * 2 + nf], 0, 0, 0);
    };

    // prologue: tile0 all 4 panels + tile1 {Akk0,Bkk0,Akk1}; 1.Bkk1 comes at t=0.ph0
    stage(0, 0, 0); stage(0, 1, 0); stage(0, 0, 1); stage(0, 1, 1);
    stage(1, 0, 0); stage(1, 1, 0); stage(1, 0, 1);
    asm volatile("s_waitcnt vmcnt(10)" ::: "memory");   // 0.Akk0/0.Bkk0 landed
    __builtin_amdgcn_s_barrier();

    for (int t = 0; t < NT; ++t) {
        const int slot = t & 1;
        // ---- phase 0: kk0, n-half 0 ----
        lda(slot, 0); ldb(slot, 0, 0);
        if (t + 1 < NT) stage(t + 1, 1, 1);            // (t+1).Bkk1 (slot^1, freed @ t-1.ph3)
        __builtin_amdgcn_s_barrier();
        asm volatile("s_waitcnt lgkmcnt(0)" ::: "memory");
        __builtin_amdgcn_sched_barrier(0);
        __builtin_amdgcn_s_setprio(1);
        mfma16(0);
        __builtin_amdgcn_s_setprio(0);
        __builtin_amdgcn_s_barrier();
        // ---- phase 1: kk0, n-half 1 (areg reused) ----
        ldb(slot, 0, 1);
        if (t + 2 < NT) stage(t + 2, 0, 0);            // (t+2).Akk0 (freed @ ph0)
        __builtin_amdgcn_s_barrier();
        asm volatile("s_waitcnt lgkmcnt(0)" ::: "memory");
        __builtin_amdgcn_sched_barrier(0);
        __builtin_amdgcn_s_setprio(1);
        mfma16(1);
        __builtin_amdgcn_s_setprio(0);
        if (t < 16)      { asm volatile("s_waitcnt vmcnt(10)" ::: "memory"); }
        else if (t == 16){ asm volatile("s_waitcnt vmcnt(8)"  ::: "memory"); }
        else             { asm volatile("s_waitcnt vmcnt(0)"  ::: "memory"); }
        __builtin_amdgcn_s_barrier();
        // ---- phase 2: kk1, n-half 0 ----
        lda(slot, 1); ldb(slot, 1, 0);
        if (t + 2 < NT) stage(t + 2, 1, 0);            // (t+2).Bkk0 (freed @ ph1)
        __builtin_amdgcn_s_barrier();
        asm volatile("s_waitcnt lgkmcnt(0)" ::: "memory");
        __builtin_amdgcn_sched_barrier(0);
        __builtin_amdgcn_s_setprio(1);
        mfma16(0);
        __builtin_amdgcn_s_setprio(0);
        __builtin_amdgcn_s_barrier();
        // ---- phase 3: kk1, n-half 1 (areg reused) ----
        ldb(slot, 1, 1);
        if (t + 2 < NT) stage(t + 2, 0, 1);            // (t+2).Akk1 (freed @ ph2)
        __builtin_amdgcn_s_barrier();
        asm volatile("s_waitcnt lgkmcnt(0)" ::: "memory");
        __builtin_amdgcn_sched_barrier(0);
        __builtin_amdgcn_s_setprio(1);
        mfma16(1);
        __builtin_amdgcn_s_setprio(0);
        if (t < 16)      { asm volatile("s_waitcnt vmcnt(10)" ::: "memory"); }
        else if (t == 16){ asm volatile("s_waitcnt vmcnt(4)"  ::: "memory"); }
        // t==17: everything already landed (ph1 gate was vmcnt(0))
        __builtin_amdgcn_s_barrier();
    }

    // epilogue: ragged max; D[row = 4q+r][col = i16]; leaf = acc + cl[col]
    int segc[4]; float clv[4];
    #pragma unroll
    for (int nf = 0; nf < 4; ++nf) {
        const int col = blockN + wn * 64 + nf * 16 + i16;
        segc[nf] = seg[col];
        clv[nf]  = cl[col];
    }
    #pragma unroll
    for (int mf = 0; mf < 8; ++mf)
        #pragma unroll
        for (int nf = 0; nf < 4; ++nf)
            #pragma unroll
            for (int r = 0; r < 4; ++r) {
                const int rl = wm * 128 + mf * 16 + 4 * q + r;
                atomicMax(&pmax[rl * 17 + segc[nf]], f2ord(acc[mf][nf][r] + clv[nf]));
            }
    __syncthreads();
    #pragma unroll
    for (int j = 0; j < 8; ++j) {
        int idx = tid + j * 512;                       // 0..4095
        pp[((long)nT << 19) + ((blockM + (idx >> 4)) << 4) + (idx & 15)] =
            pmax[(idx >> 4) * 17 + (idx & 15)];
    }
}

// ---------------- finalize: max over 4 partials + softmax ----------------
__global__ __launch_bounds__(256) void finalize(const u32* __restrict__ pp,
                                                float* __restrict__ out) {
    const int tid = threadIdx.x;
    const long row = (long)blockIdx.x * 16 + (tid >> 4);
    const int t = tid & 15;
    u32 m = 0;
    #pragma unroll
    for (int p = 0; p < 4; ++p)
        m = max(m, pp[((long)p << 19) + (row << 4) + t]);
    float logit = ord2f(m);
    float rm = logit;
    #pragma unroll
    for (int d = 8; d >= 1; d >>= 1) rm = fmaxf(rm, __shfl_xor(rm, d, 16));
    float e = __expf(logit - rm);
    float s = e;
    #pragma unroll
    for (int d = 8; d >= 1; d >>= 1) s += __shfl_xor(s, d, 16);
    out[(row << 4) + t] = e / s;
}

// ---------------- launch ----------------
extern "C" void kernel_launch(void* const* d_in, const int* in_sizes, int n_in,
                              void* d_out, int out_size, void* d_ws, size_t ws_size,
                              hipStream_t stream) {
    const float* x  = (const float*)d_in[0];
    const float* Wd = (const float*)d_in[1];
    const float* bd = (const float*)d_in[2];
    const float* Wa = (const float*)d_in[3];
    const float* ba = (const float*)d_in[4];
    const float* Wl = (const float*)d_in[5];
    const int*  seg = (const int*)d_in[6];
    float* out = (float*)d_out;

    char* ws = (char*)d_ws;
    u16*   xb   = (u16*)(ws);                      //   8,388,608 B  x bf16 [32768,128]
    u16*   w1b  = (u16*)(ws + 8388608);            //     262,144 B  W1 bf16 [1024,128]
    float* bb   = (float*)(ws + 8650752);          //       4,096 B  bias [1024]
    u16*   w1t  = (u16*)(ws + 8654848);            //     262,144 B  W1^T bf16 [128,1024]
    u16*   wsb  = (u16*)(ws + 8916992);            //   2,097,152 B  Ws bf16 [1024,1024]
    u16*   dlb  = (u16*)(ws + 11014144);           //   2,097,152 B  Dl bf16 [1024,1024]
    u16*   wcb  = (u16*)(ws + 13111296);           //     262,144 B  Wc bf16 [1024,128]
    float* clp  = (float*)(ws + 13373440);         //       4,096 B  cl fp32 [1024]
    u16*   habs = (u16*)(ws + 13377536);           //  67,108,864 B  |h| bf16 [32768,1024]
    u32*   pp   = (u32*)(ws + 80486400);           //  16,777,216 B  pooledPart u32 [4][32768][16]
    // total ws use: 97,263,616 B (~93 MiB)

    setup_all<<<2624, 256, 0, stream>>>(x, Wd, bd, Wa, ba, Wl,
                                        xb, w1b, bb, w1t, wsb, dlb, clp);
    gemm_hwc <<<dim3(8, 257), 256, 0, stream>>>(xb, w1b, bb, dlb, w1t, habs, wcb);
    gemm_leaf<<<dim3(512), 512, 0, stream>>>(habs, xb, wsb, wcb, clp, seg, pp);
    finalize <<<2048, 256, 0, stream>>>(pp, out);
}

// Round 2
// 209.677 us; speedup vs baseline: 1.0755x; 1.0755x over previous
//
#include <hip/hip_runtime.h>
#include <hip/hip_bf16.h>
#include <cstdint>
#include <cmath>

#define AS1 __attribute__((address_space(1)))
#define AS3 __attribute__((address_space(3)))

typedef unsigned short u16;
typedef uint32_t u32;
typedef __attribute__((ext_vector_type(8))) __bf16 bf16x8;
typedef __attribute__((ext_vector_type(8))) unsigned short u16x8;
typedef __attribute__((ext_vector_type(4))) float f32x4;

// fp32 -> bf16 round-to-nearest-even
__device__ __forceinline__ u16 f2bf(float f) {
    uint32_t u = __builtin_bit_cast(uint32_t, f);
    return (u16)((u + 0x7fffu + ((u >> 16) & 1u)) >> 16);
}

// order-preserving float -> u32 map (for integer atomicMax); 0 is below all reals
__device__ __forceinline__ u32 f2ord(float f) {
    u32 u = __builtin_bit_cast(u32, f);
    return u ^ (u32)(((int32_t)u >> 31) | 0x80000000);
}
__device__ __forceinline__ float ord2f(u32 v) {
    u32 u = (v & 0x80000000u) ? (v ^ 0x80000000u) : ~v;
    return __builtin_bit_cast(float, u);
}

// R16 SWIZZLE (both-sides, rule #21): LDS panels are [rows][32 u16] (64 B row
// stride). Unswizzled ds_read_b128 fragment reads collide ~4-way per 8-lane
// service batch (measured: all 1.47e7 conflict-cycles in R14 are these reads).
// Fix: chunk' = chunk ^ ((row>>1)&3) applied to the GLOBAL SOURCE at staging
// (LDS dest stays linear for global_load_lds) and to the LDS READ address.
//   stage key: (lane>>3)&3  ( == (ldsrow>>1)&3, since ldsrow = cA*16 + (lane>>2) )
//   read  key: (i16>>1)&3   ( row = wy*64 + s*16 + i16 -> only i16 survives mod 8 )

// ---------------- fused setup (control, = r13) ----------------
// ALGEBRA: relu(h)=(h+|h|)/2, relu(-h)=(|h|-h)/2  =>
//   leaf = |h| @ Ws^T + x @ Wc^T + cl
__global__ void setup_all(const float* __restrict__ x,
                          const float* __restrict__ Wd, const float* __restrict__ bd,
                          const float* __restrict__ Wa, const float* __restrict__ ba,
                          const float* __restrict__ Wl,
                          u16* __restrict__ xb, u16* __restrict__ w1b,
                          float* __restrict__ bb, u16* __restrict__ w1t,
                          u16* __restrict__ wsb, u16* __restrict__ dlb,
                          float* __restrict__ cl) {
    __shared__ float cred[256];
    const int b = blockIdx.x;
    const int tid = threadIdx.x;
    if (b < 2048) {
        long idx = (long)(b * 256 + tid) * 8;
        float4 a = *(const float4*)(x + idx);
        float4 c = *(const float4*)(x + idx + 4);
        u16x8 o;
        o[0]=f2bf(a.x); o[1]=f2bf(a.y); o[2]=f2bf(a.z); o[3]=f2bf(a.w);
        o[4]=f2bf(c.x); o[5]=f2bf(c.y); o[6]=f2bf(c.z); o[7]=f2bf(c.w);
        *(u16x8*)(xb + idx) = o;
    } else if (b < 2112) {
        int t = (b - 2048) * 256 + tid;   // 16384 threads
        int row = t >> 4, g = (t & 15) * 8;
        const float* src = nullptr;
        if (row < 511)       src = Wd + row * 128 + g;
        else if (row < 1023) src = Wa + (row - 511) * 128 + g;
        u16x8 o = 0;
        if (src) {
            #pragma unroll
            for (int j = 0; j < 8; ++j) o[j] = f2bf(src[j]);
        }
        *(u16x8*)(w1b + row * 128 + g) = o;
        #pragma unroll
        for (int j = 0; j < 8; ++j) w1t[(g + j) * 1024 + row] = o[j];
        if ((t & 15) == 0)
            bb[row] = row < 511 ? bd[row] : (row < 1023 ? ba[row - 511] : 0.f);
    } else {
        const int l0 = (b - 2112) * 2;
        const int lo = tid >> 7, g = (tid & 127) * 8;
        const float* src = Wl + (long)(l0 + lo) * 2046;
        u16x8 os, od;
        float part = 0.f;
        #pragma unroll
        for (int j = 0; j < 8; ++j) {
            int c = g + j;
            float pa = 0.f, pb = 0.f;
            if (c < 1023) { pa = src[c]; pb = src[1023 + c]; }
            os[j] = f2bf(0.5f * (pa + pb));
            float v = pa - pb;
            od[j] = f2bf(v);
            float b1 = c < 511 ? bd[c] : (c < 1023 ? ba[c - 511] : 0.f);
            part += v * b1;
        }
        *(u16x8*)(wsb + (long)(l0 + lo) * 1024 + g) = os;
        *(u16x8*)(dlb + (long)(l0 + lo) * 1024 + g) = od;
        cred[tid] = part;
        __syncthreads();
        if (tid < 2) {
            float s = 0.f;
            #pragma unroll
            for (int k = 0; k < 128; ++k) s += cred[tid * 128 + k];
            cl[l0 + tid] = 0.5f * s;
        }
    }
}

// ---------------- gemm_hwc: fused habs-GEMM + Wc-GEMM (= r14 + R16 swizzle) ------
// wc role at blockIdx.y == 0 dispatched first so its 8 long blocks overlap h-role.
__global__ __launch_bounds__(256) void gemm_hwc(
        const u16* __restrict__ xb, const u16* __restrict__ w1b,
        const float* __restrict__ bb,
        const u16* __restrict__ dlb, const u16* __restrict__ w1t,
        u16* __restrict__ habs, u16* __restrict__ wcb) {
    __shared__ union SharedU {
        struct { u16 As[2][4096]; u16 Bs[2][4096]; } s;  // 32 KB, 2 K-panels of 32
        u16 obuf[128 * 132];                             // 33.8 KB epilogue overlay
    } sh;
    const int tid  = threadIdx.x;
    const int lane = tid & 63, wave = tid >> 6;
    const int wy = wave >> 1, wx = wave & 1;
    const int i16 = lane & 15, q = lane >> 4;
    const int cA = wave * 2, srow = lane >> 2;
    const int scol = (((lane & 3) ^ ((lane >> 3) & 3))) * 8;  // source-swizzled chunk
    const int qa   = (q ^ ((i16 >> 1) & 3)) * 8;              // swizzled read chunk

    f32x4 acc[4][4];
    #pragma unroll
    for (int m = 0; m < 4; ++m)
        #pragma unroll
        for (int n = 0; n < 4; ++n) acc[m][n] = f32x4{0.f,0.f,0.f,0.f};

    if (blockIdx.y == 0) {
        // ---- wc role: Wc = 0.5*dlb@w1t^T, K=1024, BK=32 in panel 0 ----
        const long blockM = (long)blockIdx.x * 128;
        const int koff = (blockIdx.x * 4) & 31;
        const u16* a0 = dlb + (blockM + cA * 16 + srow) * 1024 + scol;
        const u16* a1 = dlb + (blockM + (cA + 1) * 16 + srow) * 1024 + scol;
        const u16* b0 = w1t + (long)(cA * 16 + srow) * 1024 + scol;
        const u16* b1 = w1t + (long)((cA + 1) * 16 + srow) * 1024 + scol;
        for (int it = 0; it < 32; ++it) {
            const int k0 = ((it + koff) & 31) << 5;
            __builtin_amdgcn_global_load_lds((const AS1 void*)(a0 + k0), (AS3 void*)&sh.s.As[0][cA * 512],       16, 0, 0);
            __builtin_amdgcn_global_load_lds((const AS1 void*)(a1 + k0), (AS3 void*)&sh.s.As[0][(cA + 1) * 512], 16, 0, 0);
            __builtin_amdgcn_global_load_lds((const AS1 void*)(b0 + k0), (AS3 void*)&sh.s.Bs[0][cA * 512],       16, 0, 0);
            __builtin_amdgcn_global_load_lds((const AS1 void*)(b1 + k0), (AS3 void*)&sh.s.Bs[0][(cA + 1) * 512], 16, 0, 0);
            __syncthreads();
            bf16x8 af[4], bfv[4];
            #pragma unroll
            for (int s = 0; s < 4; ++s) {
                af[s]  = *(const bf16x8*)&sh.s.As[0][(wy * 64 + s * 16 + i16) * 32 + qa];
                bfv[s] = *(const bf16x8*)&sh.s.Bs[0][(wx * 64 + s * 16 + i16) * 32 + qa];
            }
            #pragma unroll
            for (int sm = 0; sm < 4; ++sm)
                #pragma unroll
                for (int sn = 0; sn < 4; ++sn)
                    acc[sm][sn] = __builtin_amdgcn_mfma_f32_16x16x32_bf16(af[sm], bfv[sn], acc[sm][sn], 0, 0, 0);
            __syncthreads();
        }
        #pragma unroll
        for (int sm = 0; sm < 4; ++sm)
            #pragma unroll
            for (int sn = 0; sn < 4; ++sn) {
                const int col = wx * 64 + sn * 16 + i16;     // 0..127
                #pragma unroll
                for (int r = 0; r < 4; ++r) {
                    const long row = blockM + wy * 64 + sm * 16 + 4 * q + r;
                    wcb[row * 128 + col] = f2bf(0.5f * acc[sm][sn][r]);
                }
            }
        return;
    }

    // ---- h role: habs = |xb @ w1b^T + bb|, BK=64 x 2 iters ----
    const int xcd = blockIdx.x, yy = blockIdx.y - 1;   // yy in 0..255
    const long blockM = (long)(xcd * 32 + (yy >> 3)) * 128;
    const int  blockN = (yy & 7) * 128;
    const int  koff = (yy >> 3) & 1;

    const u16* a0 = xb + (blockM + cA * 16 + srow) * 128 + scol;
    const u16* a1 = xb + (blockM + (cA + 1) * 16 + srow) * 128 + scol;
    const u16* b0 = w1b + ((long)blockN + cA * 16 + srow) * 128 + scol;
    const u16* b1 = w1b + ((long)blockN + (cA + 1) * 16 + srow) * 128 + scol;
    for (int it = 0; it < 2; ++it) {
        const int k0 = ((it + koff) & 1) << 6;
        #pragma unroll
        for (int p = 0; p < 2; ++p) {
            const int kp = k0 + p * 32;
            __builtin_amdgcn_global_load_lds((const AS1 void*)(a0 + kp), (AS3 void*)&sh.s.As[p][cA * 512],       16, 0, 0);
            __builtin_amdgcn_global_load_lds((const AS1 void*)(a1 + kp), (AS3 void*)&sh.s.As[p][(cA + 1) * 512], 16, 0, 0);
            __builtin_amdgcn_global_load_lds((const AS1 void*)(b0 + kp), (AS3 void*)&sh.s.Bs[p][cA * 512],       16, 0, 0);
            __builtin_amdgcn_global_load_lds((const AS1 void*)(b1 + kp), (AS3 void*)&sh.s.Bs[p][(cA + 1) * 512], 16, 0, 0);
        }
        __syncthreads();
        #pragma unroll
        for (int p = 0; p < 2; ++p) {
            bf16x8 af[4], bfv[4];
            #pragma unroll
            for (int s = 0; s < 4; ++s) {
                af[s]  = *(const bf16x8*)&sh.s.As[p][(wy * 64 + s * 16 + i16) * 32 + qa];
                bfv[s] = *(const bf16x8*)&sh.s.Bs[p][(wx * 64 + s * 16 + i16) * 32 + qa];
            }
            #pragma unroll
            for (int sm = 0; sm < 4; ++sm)
                #pragma unroll
                for (int sn = 0; sn < 4; ++sn)
                    acc[sm][sn] = __builtin_amdgcn_mfma_f32_16x16x32_bf16(af[sm], bfv[sn], acc[sm][sn], 0, 0, 0);
        }
        __syncthreads();   // also guards obuf overlay of As/Bs
    }

    float bv[4];
    #pragma unroll
    for (int sn = 0; sn < 4; ++sn) bv[sn] = bb[blockN + wx * 64 + sn * 16 + i16];
    #pragma unroll
    for (int sm = 0; sm < 4; ++sm)
        #pragma unroll
        for (int sn = 0; sn < 4; ++sn)
            #pragma unroll
            for (int r = 0; r < 4; ++r)
                sh.obuf[(wy * 64 + sm * 16 + 4 * q + r) * 132 + wx * 64 + sn * 16 + i16] =
                    f2bf(fabsf(acc[sm][sn][r] + bv[sn]));
    __syncthreads();
    const int cg = (tid & 15) * 8;
    #pragma unroll
    for (int it = 0; it < 8; ++it) {
        const int row = it * 16 + (tid >> 4);
        *(u16x8*)&habs[(blockM + row) * 1024 + blockN + cg] =
            *(const u16x8*)&sh.obuf[row * 132 + cg];
    }
}

// ---------------- GEMM2': leaf = habs@Ws^T + xb@Wc^T + cl, fused ragged-max ----------
// (= r14 structure + R16 swizzle; BK=64, two linear K segments)
__global__ __launch_bounds__(256) void gemm_leaf(const u16* __restrict__ habs,
        const u16* __restrict__ xb, const u16* __restrict__ wsb,
        const u16* __restrict__ wcb, const float* __restrict__ cl,
        const int* __restrict__ seg, u32* __restrict__ pp) {
    __shared__ u16 As[2][128 * 32];
    __shared__ u16 Bs[2][128 * 32];
    __shared__ u32 pmax[128 * 16];
    const int tid  = threadIdx.x;
    const int lane = tid & 63, wave = tid >> 6;
    const int wy = wave >> 1, wx = wave & 1;
    const int i16 = lane & 15, q = lane >> 4;
    const int xcd = blockIdx.x, y = blockIdx.y;
    const int nTile = y & 7;
    const long blockM = (long)(xcd * 32 + (y >> 3)) * 128;
    const int  blockN = nTile * 128;
    const int  koff = ((y >> 3) * 2) & 15;        // rotation over 16 chunks of K=64

    #pragma unroll
    for (int j = 0; j < 8; ++j) pmax[tid + j * 256] = 0u;   // below all reals

    f32x4 acc[4][4];
    #pragma unroll
    for (int m = 0; m < 4; ++m)
        #pragma unroll
        for (int n = 0; n < 4; ++n) acc[m][n] = f32x4{0.f,0.f,0.f,0.f};

    const int cA = wave * 2, srow = lane >> 2;
    const int scol = (((lane & 3) ^ ((lane >> 3) & 3))) * 8;  // source-swizzled chunk
    const int qa   = (q ^ ((i16 >> 1) & 3)) * 8;              // swizzled read chunk
    // phase 1: habs (stride 1024) x wsb (stride 1024), 16 iters of K=64 (two linear runs)
    {
        const u16* a0 = habs + (blockM + cA * 16 + srow) * 1024 + scol;
        const u16* a1 = habs + (blockM + (cA + 1) * 16 + srow) * 1024 + scol;
        const u16* b0 = wsb + ((long)blockN + cA * 16 + srow) * 1024 + scol;
        const u16* b1 = wsb + ((long)blockN + (cA + 1) * 16 + srow) * 1024 + scol;
        auto kstep = [&](int k0) {
            #pragma unroll
            for (int p = 0; p < 2; ++p) {
                const int kp = k0 + p * 32;
                __builtin_amdgcn_global_load_lds((const AS1 void*)(a0 + kp), (AS3 void*)&As[p][cA * 512],       16, 0, 0);
                __builtin_amdgcn_global_load_lds((const AS1 void*)(a1 + kp), (AS3 void*)&As[p][(cA + 1) * 512], 16, 0, 0);
                __builtin_amdgcn_global_load_lds((const AS1 void*)(b0 + kp), (AS3 void*)&Bs[p][cA * 512],       16, 0, 0);
                __builtin_amdgcn_global_load_lds((const AS1 void*)(b1 + kp), (AS3 void*)&Bs[p][(cA + 1) * 512], 16, 0, 0);
            }
            __syncthreads();
            #pragma unroll
            for (int p = 0; p < 2; ++p) {
                bf16x8 af[4], bfv[4];
                #pragma unroll
                for (int s = 0; s < 4; ++s) {
                    af[s]  = *(const bf16x8*)&As[p][(wy * 64 + s * 16 + i16) * 32 + qa];
                    bfv[s] = *(const bf16x8*)&Bs[p][(wx * 64 + s * 16 + i16) * 32 + qa];
                }
                #pragma unroll
                for (int sm = 0; sm < 4; ++sm)
                    #pragma unroll
                    for (int sn = 0; sn < 4; ++sn)
                        acc[sm][sn] = __builtin_amdgcn_mfma_f32_16x16x32_bf16(af[sm], bfv[sn], acc[sm][sn], 0, 0, 0);
            }
            __syncthreads();
        };
        for (int it = koff; it < 16; ++it) kstep(it << 6);
        for (int it = 0; it < koff; ++it)  kstep(it << 6);
    }
    // phase 2: xb (stride 128) x wcb (stride 128), 2 iters of K=64
    {
        const u16* a0 = xb + (blockM + cA * 16 + srow) * 128 + scol;
        const u16* a1 = xb + (blockM + (cA + 1) * 16 + srow) * 128 + scol;
        const u16* b0 = wcb + ((long)blockN + cA * 16 + srow) * 128 + scol;
        const u16* b1 = wcb + ((long)blockN + (cA + 1) * 16 + srow) * 128 + scol;
        #pragma unroll
        for (int half = 0; half < 2; ++half) {
            const int k0 = half * 64;
            #pragma unroll
            for (int p = 0; p < 2; ++p) {
                const int kp = k0 + p * 32;
                __builtin_amdgcn_global_load_lds((const AS1 void*)(a0 + kp), (AS3 void*)&As[p][cA * 512],       16, 0, 0);
                __builtin_amdgcn_global_load_lds((const AS1 void*)(a1 + kp), (AS3 void*)&As[p][(cA + 1) * 512], 16, 0, 0);
                __builtin_amdgcn_global_load_lds((const AS1 void*)(b0 + kp), (AS3 void*)&Bs[p][cA * 512],       16, 0, 0);
                __builtin_amdgcn_global_load_lds((const AS1 void*)(b1 + kp), (AS3 void*)&Bs[p][(cA + 1) * 512], 16, 0, 0);
            }
            __syncthreads();
            #pragma unroll
            for (int p = 0; p < 2; ++p) {
                bf16x8 af[4], bfv[4];
                #pragma unroll
                for (int s = 0; s < 4; ++s) {
                    af[s]  = *(const bf16x8*)&As[p][(wy * 64 + s * 16 + i16) * 32 + qa];
                    bfv[s] = *(const bf16x8*)&Bs[p][(wx * 64 + s * 16 + i16) * 32 + qa];
                }
                #pragma unroll
                for (int sm = 0; sm < 4; ++sm)
                    #pragma unroll
                    for (int sn = 0; sn < 4; ++sn)
                        acc[sm][sn] = __builtin_amdgcn_mfma_f32_16x16x32_bf16(af[sm], bfv[sn], acc[sm][sn], 0, 0, 0);
            }
            __syncthreads();
        }
    }

    // epilogue: D[row = 4q + r][col = i16]; leaf = acc + cl[col]
    int segc[4]; float clv[4];
    #pragma unroll
    for (int sn = 0; sn < 4; ++sn) {
        const int col = blockN + wx * 64 + sn * 16 + i16;
        segc[sn] = seg[col];
        clv[sn]  = cl[col];
    }
    #pragma unroll
    for (int sm = 0; sm < 4; ++sm)
        #pragma unroll
        for (int sn = 0; sn < 4; ++sn)
            #pragma unroll
            for (int r = 0; r < 4; ++r) {
                const int rl = wy * 64 + sm * 16 + 4 * q + r;
                atomicMax(&pmax[rl * 16 + segc[sn]], f2ord(acc[sm][sn][r] + clv[sn]));
            }
    __syncthreads();
    #pragma unroll
    for (int j = 0; j < 8; ++j) {
        int idx = tid + j * 256;                       // 0..2047
        pp[((long)nTile << 19) + ((blockM + (idx >> 4)) << 4) + (idx & 15)] = pmax[idx];
    }
}

// ---------------- finalize: max over 8 partials + softmax ----------------
__global__ __launch_bounds__(256) void finalize(const u32* __restrict__ pp,
                                                float* __restrict__ out) {
    const int tid = threadIdx.x;
    const long row = (long)blockIdx.x * 16 + (tid >> 4);
    const int t = tid & 15;
    u32 m = 0;
    #pragma unroll
    for (int p = 0; p < 8; ++p)
        m = max(m, pp[((long)p << 19) + (row << 4) + t]);
    float logit = ord2f(m);
    float rm = logit;
    #pragma unroll
    for (int d = 8; d >= 1; d >>= 1) rm = fmaxf(rm, __shfl_xor(rm, d, 16));
    float e = __expf(logit - rm);
    float s = e;
    #pragma unroll
    for (int d = 8; d >= 1; d >>= 1) s += __shfl_xor(s, d, 16);
    out[(row << 4) + t] = e / s;
}

// ---------------- launch ----------------
extern "C" void kernel_launch(void* const* d_in, const int* in_sizes, int n_in,
                              void* d_out, int out_size, void* d_ws, size_t ws_size,
                              hipStream_t stream) {
    const float* x  = (const float*)d_in[0];
    const float* Wd = (const float*)d_in[1];
    const float* bd = (const float*)d_in[2];
    const float* Wa = (const float*)d_in[3];
    const float* ba = (const float*)d_in[4];
    const float* Wl = (const float*)d_in[5];
    const int*  seg = (const int*)d_in[6];
    float* out = (float*)d_out;

    char* ws = (char*)d_ws;
    u16*   xb   = (u16*)(ws);                      //   8,388,608 B  x bf16 [32768,128]
    u16*   w1b  = (u16*)(ws + 8388608);            //     262,144 B  W1 bf16 [1024,128]
    float* bb   = (float*)(ws + 8650752);          //       4,096 B  bias [1024]
    u16*   w1t  = (u16*)(ws + 8654848);            //     262,144 B  W1^T bf16 [128,1024]
    u16*   wsb  = (u16*)(ws + 8916992);            //   2,097,152 B  Ws bf16 [1024,1024]
    u16*   dlb  = (u16*)(ws + 11014144);           //   2,097,152 B  Dl bf16 [1024,1024]
    u16*   wcb  = (u16*)(ws + 13111296);           //     262,144 B  Wc bf16 [1024,128]
    float* clp  = (float*)(ws + 13373440);         //       4,096 B  cl fp32 [1024]
    u16*   habs = (u16*)(ws + 13377536);           //  67,108,864 B  |h| bf16 [32768,1024]
    u32*   pp   = (u32*)(ws + 80486400);           //  16,777,216 B  pooledPart u32 [8][32768][16]
    // total ws use: 97,263,616 B (~93 MiB)

    setup_all<<<2624, 256, 0, stream>>>(x, Wd, bd, Wa, ba, Wl,
                                        xb, w1b, bb, w1t, wsb, dlb, clp);
    gemm_hwc <<<dim3(8, 257), 256, 0, stream>>>(xb, w1b, bb, dlb, w1t, habs, wcb);
    gemm_leaf<<<dim3(8, 256), 256, 0, stream>>>(habs, xb, wsb, wcb, clp, seg, pp);
    finalize <<<2048, 256, 0, stream>>>(pp, out);
}

// Round 4
// 207.088 us; speedup vs baseline: 1.0890x; 1.0125x over previous
//
#include <hip/hip_runtime.h>
#include <hip/hip_bf16.h>
#include <cstdint>
#include <cmath>

#define AS1 __attribute__((address_space(1)))
#define AS3 __attribute__((address_space(3)))

typedef unsigned short u16;
typedef uint32_t u32;
typedef __attribute__((ext_vector_type(8))) __bf16 bf16x8;
typedef __attribute__((ext_vector_type(8))) unsigned short u16x8;
typedef __attribute__((ext_vector_type(4))) float f32x4;

// fp32 -> bf16 round-to-nearest-even
__device__ __forceinline__ u16 f2bf(float f) {
    uint32_t u = __builtin_bit_cast(uint32_t, f);
    return (u16)((u + 0x7fffu + ((u >> 16) & 1u)) >> 16);
}

// order-preserving float -> u32 map (for integer atomicMax); 0 is below all reals
__device__ __forceinline__ u32 f2ord(float f) {
    u32 u = __builtin_bit_cast(u32, f);
    return u ^ (u32)(((int32_t)u >> 31) | 0x80000000);
}
__device__ __forceinline__ float ord2f(u32 v) {
    u32 u = (v & 0x80000000u) ? (v ^ 0x80000000u) : ~v;
    return __builtin_bit_cast(float, u);
}

// R18 == R17 resubmitted verbatim (previous round was an infra failure:
// "container failed twice", no kernel verdict). Audit found no OOB/hang path.
//
// SWIZZLE (R16-proven, both-sides involution, rule #21): LDS panels are
// [rows][32 u16] (64 B row stride). LDS[row][chunk c] holds GLOBAL chunk
// c ^ key(row), key(row) = (row>>1)&3 (staged via pre-swizzled global source,
// LDS dest stays linear for global_load_lds). Read: lane (i16,q) reads chunk
// q ^ key(i16) -> gets global chunk q, i.e. register contents are the STANDARD
// MFMA fragment; only LDS placement is permuted. 8-lane service batches span
// all 32 banks -> conflict-free (verified: 1.47e7 -> 5.3e6 conflict cycles,
// residual = epilogue atomics).
//   stage key: (tid>>3)&3   ( == (destrow>>1)&3 )
//   read  key: (i16>>1)&3

// ---------------- fused setup (control, = r13) ----------------
// ALGEBRA: relu(h)=(h+|h|)/2, relu(-h)=(|h|-h)/2  =>
//   leaf = |h| @ Ws^T + x @ Wc^T + cl
__global__ void setup_all(const float* __restrict__ x,
                          const float* __restrict__ Wd, const float* __restrict__ bd,
                          const float* __restrict__ Wa, const float* __restrict__ ba,
                          const float* __restrict__ Wl,
                          u16* __restrict__ xb, u16* __restrict__ w1b,
                          float* __restrict__ bb, u16* __restrict__ w1t,
                          u16* __restrict__ wsb, u16* __restrict__ dlb,
                          float* __restrict__ cl) {
    __shared__ float cred[256];
    const int b = blockIdx.x;
    const int tid = threadIdx.x;
    if (b < 2048) {
        long idx = (long)(b * 256 + tid) * 8;
        float4 a = *(const float4*)(x + idx);
        float4 c = *(const float4*)(x + idx + 4);
        u16x8 o;
        o[0]=f2bf(a.x); o[1]=f2bf(a.y); o[2]=f2bf(a.z); o[3]=f2bf(a.w);
        o[4]=f2bf(c.x); o[5]=f2bf(c.y); o[6]=f2bf(c.z); o[7]=f2bf(c.w);
        *(u16x8*)(xb + idx) = o;
    } else if (b < 2112) {
        int t = (b - 2048) * 256 + tid;   // 16384 threads
        int row = t >> 4, g = (t & 15) * 8;
        const float* src = nullptr;
        if (row < 511)       src = Wd + row * 128 + g;
        else if (row < 1023) src = Wa + (row - 511) * 128 + g;
        u16x8 o = 0;
        if (src) {
            #pragma unroll
            for (int j = 0; j < 8; ++j) o[j] = f2bf(src[j]);
        }
        *(u16x8*)(w1b + row * 128 + g) = o;
        #pragma unroll
        for (int j = 0; j < 8; ++j) w1t[(g + j) * 1024 + row] = o[j];
        if ((t & 15) == 0)
            bb[row] = row < 511 ? bd[row] : (row < 1023 ? ba[row - 511] : 0.f);
    } else {
        const int l0 = (b - 2112) * 2;
        const int lo = tid >> 7, g = (tid & 127) * 8;
        const float* src = Wl + (long)(l0 + lo) * 2046;
        u16x8 os, od;
        float part = 0.f;
        #pragma unroll
        for (int j = 0; j < 8; ++j) {
            int c = g + j;
            float pa = 0.f, pb = 0.f;
            if (c < 1023) { pa = src[c]; pb = src[1023 + c]; }
            os[j] = f2bf(0.5f * (pa + pb));
            float v = pa - pb;
            od[j] = f2bf(v);
            float b1 = c < 511 ? bd[c] : (c < 1023 ? ba[c - 511] : 0.f);
            part += v * b1;
        }
        *(u16x8*)(wsb + (long)(l0 + lo) * 1024 + g) = os;
        *(u16x8*)(dlb + (long)(l0 + lo) * 1024 + g) = od;
        cred[tid] = part;
        __syncthreads();
        if (tid < 2) {
            float s = 0.f;
            #pragma unroll
            for (int k = 0; k < 128; ++k) s += cred[tid * 128 + k];
            cl[l0 + tid] = 0.5f * s;
        }
    }
}

// ---------------- gemm_hwc: fused habs-GEMM + Wc-GEMM (= R16, unchanged) --------
__global__ __launch_bounds__(256) void gemm_hwc(
        const u16* __restrict__ xb, const u16* __restrict__ w1b,
        const float* __restrict__ bb,
        const u16* __restrict__ dlb, const u16* __restrict__ w1t,
        u16* __restrict__ habs, u16* __restrict__ wcb) {
    __shared__ union SharedU {
        struct { u16 As[2][4096]; u16 Bs[2][4096]; } s;  // 32 KB, 2 K-panels of 32
        u16 obuf[128 * 132];                             // 33.8 KB epilogue overlay
    } sh;
    const int tid  = threadIdx.x;
    const int lane = tid & 63, wave = tid >> 6;
    const int wy = wave >> 1, wx = wave & 1;
    const int i16 = lane & 15, q = lane >> 4;
    const int cA = wave * 2, srow = lane >> 2;
    const int scol = (((lane & 3) ^ ((lane >> 3) & 3))) * 8;  // source-swizzled chunk
    const int qa   = (q ^ ((i16 >> 1) & 3)) * 8;              // swizzled read chunk

    f32x4 acc[4][4];
    #pragma unroll
    for (int m = 0; m < 4; ++m)
        #pragma unroll
        for (int n = 0; n < 4; ++n) acc[m][n] = f32x4{0.f,0.f,0.f,0.f};

    if (blockIdx.y == 0) {
        // ---- wc role: Wc = 0.5*dlb@w1t^T, K=1024, BK=32 in panel 0 ----
        const long blockM = (long)blockIdx.x * 128;
        const int koff = (blockIdx.x * 4) & 31;
        const u16* a0 = dlb + (blockM + cA * 16 + srow) * 1024 + scol;
        const u16* a1 = dlb + (blockM + (cA + 1) * 16 + srow) * 1024 + scol;
        const u16* b0 = w1t + (long)(cA * 16 + srow) * 1024 + scol;
        const u16* b1 = w1t + (long)((cA + 1) * 16 + srow) * 1024 + scol;
        for (int it = 0; it < 32; ++it) {
            const int k0 = ((it + koff) & 31) << 5;
            __builtin_amdgcn_global_load_lds((const AS1 void*)(a0 + k0), (AS3 void*)&sh.s.As[0][cA * 512],       16, 0, 0);
            __builtin_amdgcn_global_load_lds((const AS1 void*)(a1 + k0), (AS3 void*)&sh.s.As[0][(cA + 1) * 512], 16, 0, 0);
            __builtin_amdgcn_global_load_lds((const AS1 void*)(b0 + k0), (AS3 void*)&sh.s.Bs[0][cA * 512],       16, 0, 0);
            __builtin_amdgcn_global_load_lds((const AS1 void*)(b1 + k0), (AS3 void*)&sh.s.Bs[0][(cA + 1) * 512], 16, 0, 0);
            __syncthreads();
            bf16x8 af[4], bfv[4];
            #pragma unroll
            for (int s = 0; s < 4; ++s) {
                af[s]  = *(const bf16x8*)&sh.s.As[0][(wy * 64 + s * 16 + i16) * 32 + qa];
                bfv[s] = *(const bf16x8*)&sh.s.Bs[0][(wx * 64 + s * 16 + i16) * 32 + qa];
            }
            #pragma unroll
            for (int sm = 0; sm < 4; ++sm)
                #pragma unroll
                for (int sn = 0; sn < 4; ++sn)
                    acc[sm][sn] = __builtin_amdgcn_mfma_f32_16x16x32_bf16(af[sm], bfv[sn], acc[sm][sn], 0, 0, 0);
            __syncthreads();
        }
        #pragma unroll
        for (int sm = 0; sm < 4; ++sm)
            #pragma unroll
            for (int sn = 0; sn < 4; ++sn) {
                const int col = wx * 64 + sn * 16 + i16;     // 0..127
                #pragma unroll
                for (int r = 0; r < 4; ++r) {
                    const long row = blockM + wy * 64 + sm * 16 + 4 * q + r;
                    wcb[row * 128 + col] = f2bf(0.5f * acc[sm][sn][r]);
                }
            }
        return;
    }

    // ---- h role: habs = |xb @ w1b^T + bb|, BK=64 x 2 iters ----
    const int xcd = blockIdx.x, yy = blockIdx.y - 1;   // yy in 0..255
    const long blockM = (long)(xcd * 32 + (yy >> 3)) * 128;
    const int  blockN = (yy & 7) * 128;
    const int  koff = (yy >> 3) & 1;

    const u16* a0 = xb + (blockM + cA * 16 + srow) * 128 + scol;
    const u16* a1 = xb + (blockM + (cA + 1) * 16 + srow) * 128 + scol;
    const u16* b0 = w1b + ((long)blockN + cA * 16 + srow) * 128 + scol;
    const u16* b1 = w1b + ((long)blockN + (cA + 1) * 16 + srow) * 128 + scol;
    for (int it = 0; it < 2; ++it) {
        const int k0 = ((it + koff) & 1) << 6;
        #pragma unroll
        for (int p = 0; p < 2; ++p) {
            const int kp = k0 + p * 32;
            __builtin_amdgcn_global_load_lds((const AS1 void*)(a0 + kp), (AS3 void*)&sh.s.As[p][cA * 512],       16, 0, 0);
            __builtin_amdgcn_global_load_lds((const AS1 void*)(a1 + kp), (AS3 void*)&sh.s.As[p][(cA + 1) * 512], 16, 0, 0);
            __builtin_amdgcn_global_load_lds((const AS1 void*)(b0 + kp), (AS3 void*)&sh.s.Bs[p][cA * 512],       16, 0, 0);
            __builtin_amdgcn_global_load_lds((const AS1 void*)(b1 + kp), (AS3 void*)&sh.s.Bs[p][(cA + 1) * 512], 16, 0, 0);
        }
        __syncthreads();
        #pragma unroll
        for (int p = 0; p < 2; ++p) {
            bf16x8 af[4], bfv[4];
            #pragma unroll
            for (int s = 0; s < 4; ++s) {
                af[s]  = *(const bf16x8*)&sh.s.As[p][(wy * 64 + s * 16 + i16) * 32 + qa];
                bfv[s] = *(const bf16x8*)&sh.s.Bs[p][(wx * 64 + s * 16 + i16) * 32 + qa];
            }
            #pragma unroll
            for (int sm = 0; sm < 4; ++sm)
                #pragma unroll
                for (int sn = 0; sn < 4; ++sn)
                    acc[sm][sn] = __builtin_amdgcn_mfma_f32_16x16x32_bf16(af[sm], bfv[sn], acc[sm][sn], 0, 0, 0);
        }
        __syncthreads();   // also guards obuf overlay of As/Bs
    }

    float bv[4];
    #pragma unroll
    for (int sn = 0; sn < 4; ++sn) bv[sn] = bb[blockN + wx * 64 + sn * 16 + i16];
    #pragma unroll
    for (int sm = 0; sm < 4; ++sm)
        #pragma unroll
        for (int sn = 0; sn < 4; ++sn)
            #pragma unroll
            for (int r = 0; r < 4; ++r)
                sh.obuf[(wy * 64 + sm * 16 + 4 * q + r) * 132 + wx * 64 + sn * 16 + i16] =
                    f2bf(fabsf(acc[sm][sn][r] + bv[sn]));
    __syncthreads();
    const int cg = (tid & 15) * 8;
    #pragma unroll
    for (int it = 0; it < 8; ++it) {
        const int row = it * 16 + (tid >> 4);
        *(u16x8*)&habs[(blockM + row) * 1024 + blockN + cg] =
            *(const u16x8*)&sh.obuf[row * 132 + cg];
    }
}

// ---------------- GEMM2 (R17): 256^2-tile, 8-wave, BK=32, 4-slot pipeline --------
// leaf = habs@Ws^T + xb@Wc^T + cl, fused ragged-max.
// K-tiles t=0..31: habs/wsb (stride 1024); t=32,33,34,35: xb/wcb (stride 128).
// Slot discipline: tile t lives in slot t&3; during tile t we stage tile t+2
// (slot (t+2)&3 — NEVER the slot being read; its last reader was t-2, done).
// Single gate per tile: vmcnt(4) at end of ph1 (outstanding = stage(t+2)'s 4
// ops) guarantees tile t+1 fully resident. Prefetch distance ~4 phases.
// Phases (2 per tile, m-half split, balanced 8/4 reads, breg persists):
//   ph0: lda(mh0) 4 + ldb 4; stageA(t+2); bar; lgkm0; SB; prio1; 16 MFMA; prio0; bar
//   ph1: lda(mh1) 4;         stageB(t+2); bar; lgkm0; SB; prio1; 16 MFMA; prio0; gate; bar
__global__ __launch_bounds__(512, 2) void gemm_leaf(const u16* __restrict__ habs,
        const u16* __restrict__ xb, const u16* __restrict__ wsb,
        const u16* __restrict__ wcb, const float* __restrict__ cl,
        const int* __restrict__ seg, u32* __restrict__ pp) {
    __shared__ __align__(16) u16 As[4][256 * 32];   // 64 KB, 4 K32-slots
    __shared__ __align__(16) u16 Bs[4][256 * 32];   // 64 KB
    __shared__ u32 pmax[256 * 16];                  // 16 KB
    const int tid  = threadIdx.x;
    const int lane = tid & 63, w = tid >> 6;
    const int wm = w >> 2, wn = w & 3;              // 2x4 wave grid, wave tile 128x64
    const int i16 = lane & 15, q = lane >> 4;

    // XCD-aware swizzle over 512 blocks (512%8==0 -> bijective); 4 nT of one mT
    // land on the same XCD -> A-panel L2 reuse x4.
    const int bid  = blockIdx.x;
    const int wgid = (bid & 7) * 64 + (bid >> 3);
    const int mT = wgid >> 2, nT = wgid & 3;
    const long blockM = (long)mT * 256;
    const int  blockN = nT * 256;

    #pragma unroll
    for (int j = 0; j < 8; ++j) pmax[tid + j * 512] = 0u;   // below all reals

    // staging: thread covers rows {tid>>2, 128+(tid>>2)}, dest chunk tid&3 (linear),
    // source chunk (tid&3)^key (pre-swizzle).
    const int r0 = tid >> 2;
    const int scol = (((tid & 3) ^ ((tid >> 3) & 3))) * 8;
    const u16* gA1 = habs + (blockM + r0) * 1024 + scol;
    const u16* gB1 = wsb  + (long)(blockN + r0) * 1024 + scol;
    const u16* gA2 = xb   + (blockM + r0) * 128 + scol;
    const u16* gB2 = wcb  + (long)(blockN + r0) * 128 + scol;
    const int ldsb = w * 512;                       // wave-uniform dest base (u16)

    auto stageA = [&](int tt) {
        u16* dst = &As[tt & 3][ldsb];
        const u16* g; int jstr;
        if (tt < 32) { g = gA1 + tt * 32;        jstr = 128 * 1024; }
        else         { g = gA2 + (tt - 32) * 32; jstr = 128 * 128; }
        __builtin_amdgcn_global_load_lds((const AS1 void*)g,          (AS3 void*)dst,          16, 0, 0);
        __builtin_amdgcn_global_load_lds((const AS1 void*)(g + jstr), (AS3 void*)(dst + 4096), 16, 0, 0);
    };
    auto stageB = [&](int tt) {
        u16* dst = &Bs[tt & 3][ldsb];
        const u16* g; int jstr;
        if (tt < 32) { g = gB1 + tt * 32;        jstr = 128 * 1024; }
        else         { g = gB2 + (tt - 32) * 32; jstr = 128 * 128; }
        __builtin_amdgcn_global_load_lds((const AS1 void*)g,          (AS3 void*)dst,          16, 0, 0);
        __builtin_amdgcn_global_load_lds((const AS1 void*)(g + jstr), (AS3 void*)(dst + 4096), 16, 0, 0);
    };

    f32x4 acc[8][4];
    #pragma unroll
    for (int m = 0; m < 8; ++m)
        #pragma unroll
        for (int n = 0; n < 4; ++n) acc[m][n] = f32x4{0.f,0.f,0.f,0.f};
    bf16x8 areg[4], breg[4];

    const int rdc = (q ^ ((i16 >> 1) & 3)) * 8;     // swizzled read chunk (u16 off)
    auto lda = [&](int slot, int mh) {
        #pragma unroll
        for (int mf = 0; mf < 4; ++mf)
            areg[mf] = *(const bf16x8*)&As[slot][(wm * 128 + mh * 64 + mf * 16 + i16) * 32 + rdc];
    };
    auto ldb = [&](int slot) {
        #pragma unroll
        for (int nf = 0; nf < 4; ++nf)
            breg[nf] = *(const bf16x8*)&Bs[slot][(wn * 64 + nf * 16 + i16) * 32 + rdc];
    };
    auto mf16 = [&](int mh) {
        #pragma unroll
        for (int mf = 0; mf < 4; ++mf)
            #pragma unroll
            for (int nf = 0; nf < 4; ++nf)
                acc[mh * 4 + mf][nf] = __builtin_amdgcn_mfma_f32_16x16x32_bf16(
                    areg[mf], breg[nf], acc[mh * 4 + mf][nf], 0, 0, 0);
    };

    // prologue: tiles 0 and 1; gate so tile 0 is resident
    stageA(0); stageB(0); stageA(1); stageB(1);
    asm volatile("s_waitcnt vmcnt(4)" ::: "memory");
    __builtin_amdgcn_s_barrier();

    for (int t = 0; t < 36; ++t) {
        const int slot = t & 3;
        // ---- phase 0: m-half 0 ----
        lda(slot, 0); ldb(slot);
        if (t + 2 < 36) stageA(t + 2);
        __builtin_amdgcn_s_barrier();
        asm volatile("s_waitcnt lgkmcnt(0)" ::: "memory");
        __builtin_amdgcn_sched_barrier(0);
        __builtin_amdgcn_s_setprio(1);
        mf16(0);
        __builtin_amdgcn_s_setprio(0);
        __builtin_amdgcn_s_barrier();
        // ---- phase 1: m-half 1 (breg reused) ----
        lda(slot, 1);
        if (t + 2 < 36) stageB(t + 2);
        __builtin_amdgcn_s_barrier();
        asm volatile("s_waitcnt lgkmcnt(0)" ::: "memory");
        __builtin_amdgcn_sched_barrier(0);
        __builtin_amdgcn_s_setprio(1);
        mf16(1);
        __builtin_amdgcn_s_setprio(0);
        if (t < 34)       { asm volatile("s_waitcnt vmcnt(4)" ::: "memory"); }
        else if (t == 34) { asm volatile("s_waitcnt vmcnt(0)" ::: "memory"); }
        __builtin_amdgcn_s_barrier();
    }

    // epilogue: ragged max; D[row = 4q + r][col = i16]; leaf = acc + cl[col]
    int segc[4]; float clv[4];
    #pragma unroll
    for (int nf = 0; nf < 4; ++nf) {
        const int col = blockN + wn * 64 + nf * 16 + i16;
        segc[nf] = seg[col];
        clv[nf]  = cl[col];
    }
    #pragma unroll
    for (int mf = 0; mf < 8; ++mf)
        #pragma unroll
        for (int nf = 0; nf < 4; ++nf)
            #pragma unroll
            for (int r = 0; r < 4; ++r) {
                const int rl = wm * 128 + mf * 16 + 4 * q + r;
                atomicMax(&pmax[rl * 16 + segc[nf]], f2ord(acc[mf][nf][r] + clv[nf]));
            }
    __syncthreads();
    #pragma unroll
    for (int j = 0; j < 8; ++j) {
        int idx = tid + j * 512;                       // 0..4095
        pp[((long)nT << 19) + ((blockM + (idx >> 4)) << 4) + (idx & 15)] = pmax[idx];
    }
}

// ---------------- finalize: max over 4 partials + softmax ----------------
__global__ __launch_bounds__(256) void finalize(const u32* __restrict__ pp,
                                                float* __restrict__ out) {
    const int tid = threadIdx.x;
    const long row = (long)blockIdx.x * 16 + (tid >> 4);
    const int t = tid & 15;
    u32 m = 0;
    #pragma unroll
    for (int p = 0; p < 4; ++p)
        m = max(m, pp[((long)p << 19) + (row << 4) + t]);
    float logit = ord2f(m);
    float rm = logit;
    #pragma unroll
    for (int d = 8; d >= 1; d >>= 1) rm = fmaxf(rm, __shfl_xor(rm, d, 16));
    float e = __expf(logit - rm);
    float s = e;
    #pragma unroll
    for (int d = 8; d >= 1; d >>= 1) s += __shfl_xor(s, d, 16);
    out[(row << 4) + t] = e / s;
}

// ---------------- launch ----------------
extern "C" void kernel_launch(void* const* d_in, const int* in_sizes, int n_in,
                              void* d_out, int out_size, void* d_ws, size_t ws_size,
                              hipStream_t stream) {
    const float* x  = (const float*)d_in[0];
    const float* Wd = (const float*)d_in[1];
    const float* bd = (const float*)d_in[2];
    const float* Wa = (const float*)d_in[3];
    const float* ba = (const float*)d_in[4];
    const float* Wl = (const float*)d_in[5];
    const int*  seg = (const int*)d_in[6];
    float* out = (float*)d_out;

    char* ws = (char*)d_ws;
    u16*   xb   = (u16*)(ws);                      //   8,388,608 B  x bf16 [32768,128]
    u16*   w1b  = (u16*)(ws + 8388608);            //     262,144 B  W1 bf16 [1024,128]
    float* bb   = (float*)(ws + 8650752);          //       4,096 B  bias [1024]
    u16*   w1t  = (u16*)(ws + 8654848);            //     262,144 B  W1^T bf16 [128,1024]
    u16*   wsb  = (u16*)(ws + 8916992);            //   2,097,152 B  Ws bf16 [1024,1024]
    u16*   dlb  = (u16*)(ws + 11014144);           //   2,097,152 B  Dl bf16 [1024,1024]
    u16*   wcb  = (u16*)(ws + 13111296);           //     262,144 B  Wc bf16 [1024,128]
    float* clp  = (float*)(ws + 13373440);         //       4,096 B  cl fp32 [1024]
    u16*   habs = (u16*)(ws + 13377536);           //  67,108,864 B  |h| bf16 [32768,1024]
    u32*   pp   = (u32*)(ws + 80486400);           //  16,777,216 B  pooledPart u32 [4][32768][16]
    // total ws use: 97,263,616 B (~93 MiB)

    setup_all<<<2624, 256, 0, stream>>>(x, Wd, bd, Wa, ba, Wl,
                                        xb, w1b, bb, w1t, wsb, dlb, clp);
    gemm_hwc <<<dim3(8, 257), 256, 0, stream>>>(xb, w1b, bb, dlb, w1t, habs, wcb);
    gemm_leaf<<<dim3(512), 512, 0, stream>>>(habs, xb, wsb, wcb, clp, seg, pp);
    finalize <<<2048, 256, 0, stream>>>(pp, out);
}

// Round 5
// 199.836 us; speedup vs baseline: 1.1285x; 1.0363x over previous
//
#include <hip/hip_runtime.h>
#include <hip/hip_bf16.h>
#include <cstdint>
#include <cmath>

#define AS1 __attribute__((address_space(1)))
#define AS3 __attribute__((address_space(3)))

typedef unsigned short u16;
typedef uint32_t u32;
typedef __attribute__((ext_vector_type(8))) __bf16 bf16x8;
typedef __attribute__((ext_vector_type(8))) unsigned short u16x8;
typedef __attribute__((ext_vector_type(4))) float f32x4;

// fp32 -> bf16 round-to-nearest-even
__device__ __forceinline__ u16 f2bf(float f) {
    uint32_t u = __builtin_bit_cast(uint32_t, f);
    return (u16)((u + 0x7fffu + ((u >> 16) & 1u)) >> 16);
}

// order-preserving float -> u32 map (for integer atomicMax); 0 is below all reals
__device__ __forceinline__ u32 f2ord(float f) {
    u32 u = __builtin_bit_cast(u32, f);
    return u ^ (u32)(((int32_t)u >> 31) | 0x80000000);
}
__device__ __forceinline__ float ord2f(u32 v) {
    u32 u = (v & 0x80000000u) ? (v ^ 0x80000000u) : ~v;
    return __builtin_bit_cast(float, u);
}

// SWIZZLE (R16-proven, both-sides involution, rule #21): LDS panels are
// [rows][32 u16] (64 B row stride). LDS[row][chunk c] holds GLOBAL chunk
// c ^ key(row), key(row) = (row>>1)&3 (staged via pre-swizzled global source,
// LDS dest stays linear for global_load_lds). Read: lane (i16,q) reads chunk
// q ^ key(i16) -> standard MFMA fragment in registers; only LDS placement is
// permuted. Conflict-free (verified: residual 5.3e6 conflict-cycles = epilogue
// atomics exactly; main-loop reads are clean).
//   stage key: (tid>>3)&3   ( == (destrow>>1)&3 )
//   read  key: (i16>>1)&3

// ---------------- fused setup (= r13 + R19 pooled zero-init) ----------------
// ALGEBRA: relu(h)=(h+|h|)/2, relu(-h)=(|h|-h)/2  =>
//   leaf = |h| @ Ws^T + x @ Wc^T + cl
__global__ void setup_all(const float* __restrict__ x,
                          const float* __restrict__ Wd, const float* __restrict__ bd,
                          const float* __restrict__ Wa, const float* __restrict__ ba,
                          const float* __restrict__ Wl,
                          u16* __restrict__ xb, u16* __restrict__ w1b,
                          float* __restrict__ bb, u16* __restrict__ w1t,
                          u16* __restrict__ wsb, u16* __restrict__ dlb,
                          float* __restrict__ cl, u32* __restrict__ pooled) {
    __shared__ float cred[256];
    const int b = blockIdx.x;
    const int tid = threadIdx.x;
    if (b < 2048) {
        long idx = (long)(b * 256 + tid) * 8;
        float4 a = *(const float4*)(x + idx);
        float4 c = *(const float4*)(x + idx + 4);
        u16x8 o;
        o[0]=f2bf(a.x); o[1]=f2bf(a.y); o[2]=f2bf(a.z); o[3]=f2bf(a.w);
        o[4]=f2bf(c.x); o[5]=f2bf(c.y); o[6]=f2bf(c.z); o[7]=f2bf(c.w);
        *(u16x8*)(xb + idx) = o;
    } else if (b < 2112) {
        int t = (b - 2048) * 256 + tid;   // 16384 threads
        int row = t >> 4, g = (t & 15) * 8;
        const float* src = nullptr;
        if (row < 511)       src = Wd + row * 128 + g;
        else if (row < 1023) src = Wa + (row - 511) * 128 + g;
        u16x8 o = 0;
        if (src) {
            #pragma unroll
            for (int j = 0; j < 8; ++j) o[j] = f2bf(src[j]);
        }
        *(u16x8*)(w1b + row * 128 + g) = o;
        #pragma unroll
        for (int j = 0; j < 8; ++j) w1t[(g + j) * 1024 + row] = o[j];
        if ((t & 15) == 0)
            bb[row] = row < 511 ? bd[row] : (row < 1023 ? ba[row - 511] : 0.f);
    } else if (b < 2624) {
        const int l0 = (b - 2112) * 2;
        const int lo = tid >> 7, g = (tid & 127) * 8;
        const float* src = Wl + (long)(l0 + lo) * 2046;
        u16x8 os, od;
        float part = 0.f;
        #pragma unroll
        for (int j = 0; j < 8; ++j) {
            int c = g + j;
            float pa = 0.f, pb = 0.f;
            if (c < 1023) { pa = src[c]; pb = src[1023 + c]; }
            os[j] = f2bf(0.5f * (pa + pb));
            float v = pa - pb;
            od[j] = f2bf(v);
            float b1 = c < 511 ? bd[c] : (c < 1023 ? ba[c - 511] : 0.f);
            part += v * b1;
        }
        *(u16x8*)(wsb + (long)(l0 + lo) * 1024 + g) = os;
        *(u16x8*)(dlb + (long)(l0 + lo) * 1024 + g) = od;
        cred[tid] = part;
        __syncthreads();
        if (tid < 2) {
            float s = 0.f;
            #pragma unroll
            for (int k = 0; k < 128; ++k) s += cred[tid * 128 + k];
            cl[l0 + tid] = 0.5f * s;
        }
    } else {
        // zero pooled[32768][16] u32 (2 MB) — must happen every iteration
        uint4* p4 = (uint4*)pooled;            // 131072 uint4
        const int base = (b - 2624) * 16384;   // 8 blocks x 16384 uint4
        #pragma unroll
        for (int j = 0; j < 64; ++j)
            p4[base + tid + j * 256] = uint4{0u, 0u, 0u, 0u};
    }
}

// ---------------- gemm_hwc: fused habs-GEMM + Wc-GEMM (= R16, unchanged) --------
__global__ __launch_bounds__(256) void gemm_hwc(
        const u16* __restrict__ xb, const u16* __restrict__ w1b,
        const float* __restrict__ bb,
        const u16* __restrict__ dlb, const u16* __restrict__ w1t,
        u16* __restrict__ habs, u16* __restrict__ wcb) {
    __shared__ union SharedU {
        struct { u16 As[2][4096]; u16 Bs[2][4096]; } s;  // 32 KB, 2 K-panels of 32
        u16 obuf[128 * 132];                             // 33.8 KB epilogue overlay
    } sh;
    const int tid  = threadIdx.x;
    const int lane = tid & 63, wave = tid >> 6;
    const int wy = wave >> 1, wx = wave & 1;
    const int i16 = lane & 15, q = lane >> 4;
    const int cA = wave * 2, srow = lane >> 2;
    const int scol = (((lane & 3) ^ ((lane >> 3) & 3))) * 8;  // source-swizzled chunk
    const int qa   = (q ^ ((i16 >> 1) & 3)) * 8;              // swizzled read chunk

    f32x4 acc[4][4];
    #pragma unroll
    for (int m = 0; m < 4; ++m)
        #pragma unroll
        for (int n = 0; n < 4; ++n) acc[m][n] = f32x4{0.f,0.f,0.f,0.f};

    if (blockIdx.y == 0) {
        // ---- wc role: Wc = 0.5*dlb@w1t^T, K=1024, BK=32 in panel 0 ----
        const long blockM = (long)blockIdx.x * 128;
        const int koff = (blockIdx.x * 4) & 31;
        const u16* a0 = dlb + (blockM + cA * 16 + srow) * 1024 + scol;
        const u16* a1 = dlb + (blockM + (cA + 1) * 16 + srow) * 1024 + scol;
        const u16* b0 = w1t + (long)(cA * 16 + srow) * 1024 + scol;
        const u16* b1 = w1t + (long)((cA + 1) * 16 + srow) * 1024 + scol;
        for (int it = 0; it < 32; ++it) {
            const int k0 = ((it + koff) & 31) << 5;
            __builtin_amdgcn_global_load_lds((const AS1 void*)(a0 + k0), (AS3 void*)&sh.s.As[0][cA * 512],       16, 0, 0);
            __builtin_amdgcn_global_load_lds((const AS1 void*)(a1 + k0), (AS3 void*)&sh.s.As[0][(cA + 1) * 512], 16, 0, 0);
            __builtin_amdgcn_global_load_lds((const AS1 void*)(b0 + k0), (AS3 void*)&sh.s.Bs[0][cA * 512],       16, 0, 0);
            __builtin_amdgcn_global_load_lds((const AS1 void*)(b1 + k0), (AS3 void*)&sh.s.Bs[0][(cA + 1) * 512], 16, 0, 0);
            __syncthreads();
            bf16x8 af[4], bfv[4];
            #pragma unroll
            for (int s = 0; s < 4; ++s) {
                af[s]  = *(const bf16x8*)&sh.s.As[0][(wy * 64 + s * 16 + i16) * 32 + qa];
                bfv[s] = *(const bf16x8*)&sh.s.Bs[0][(wx * 64 + s * 16 + i16) * 32 + qa];
            }
            #pragma unroll
            for (int sm = 0; sm < 4; ++sm)
                #pragma unroll
                for (int sn = 0; sn < 4; ++sn)
                    acc[sm][sn] = __builtin_amdgcn_mfma_f32_16x16x32_bf16(af[sm], bfv[sn], acc[sm][sn], 0, 0, 0);
            __syncthreads();
        }
        #pragma unroll
        for (int sm = 0; sm < 4; ++sm)
            #pragma unroll
            for (int sn = 0; sn < 4; ++sn) {
                const int col = wx * 64 + sn * 16 + i16;     // 0..127
                #pragma unroll
                for (int r = 0; r < 4; ++r) {
                    const long row = blockM + wy * 64 + sm * 16 + 4 * q + r;
                    wcb[row * 128 + col] = f2bf(0.5f * acc[sm][sn][r]);
                }
            }
        return;
    }

    // ---- h role: habs = |xb @ w1b^T + bb|, BK=64 x 2 iters ----
    const int xcd = blockIdx.x, yy = blockIdx.y - 1;   // yy in 0..255
    const long blockM = (long)(xcd * 32 + (yy >> 3)) * 128;
    const int  blockN = (yy & 7) * 128;
    const int  koff = (yy >> 3) & 1;

    const u16* a0 = xb + (blockM + cA * 16 + srow) * 128 + scol;
    const u16* a1 = xb + (blockM + (cA + 1) * 16 + srow) * 128 + scol;
    const u16* b0 = w1b + ((long)blockN + cA * 16 + srow) * 128 + scol;
    const u16* b1 = w1b + ((long)blockN + (cA + 1) * 16 + srow) * 128 + scol;
    for (int it = 0; it < 2; ++it) {
        const int k0 = ((it + koff) & 1) << 6;
        #pragma unroll
        for (int p = 0; p < 2; ++p) {
            const int kp = k0 + p * 32;
            __builtin_amdgcn_global_load_lds((const AS1 void*)(a0 + kp), (AS3 void*)&sh.s.As[p][cA * 512],       16, 0, 0);
            __builtin_amdgcn_global_load_lds((const AS1 void*)(a1 + kp), (AS3 void*)&sh.s.As[p][(cA + 1) * 512], 16, 0, 0);
            __builtin_amdgcn_global_load_lds((const AS1 void*)(b0 + kp), (AS3 void*)&sh.s.Bs[p][cA * 512],       16, 0, 0);
            __builtin_amdgcn_global_load_lds((const AS1 void*)(b1 + kp), (AS3 void*)&sh.s.Bs[p][(cA + 1) * 512], 16, 0, 0);
        }
        __syncthreads();
        #pragma unroll
        for (int p = 0; p < 2; ++p) {
            bf16x8 af[4], bfv[4];
            #pragma unroll
            for (int s = 0; s < 4; ++s) {
                af[s]  = *(const bf16x8*)&sh.s.As[p][(wy * 64 + s * 16 + i16) * 32 + qa];
                bfv[s] = *(const bf16x8*)&sh.s.Bs[p][(wx * 64 + s * 16 + i16) * 32 + qa];
            }
            #pragma unroll
            for (int sm = 0; sm < 4; ++sm)
                #pragma unroll
                for (int sn = 0; sn < 4; ++sn)
                    acc[sm][sn] = __builtin_amdgcn_mfma_f32_16x16x32_bf16(af[sm], bfv[sn], acc[sm][sn], 0, 0, 0);
        }
        __syncthreads();   // also guards obuf overlay of As/Bs
    }

    float bv[4];
    #pragma unroll
    for (int sn = 0; sn < 4; ++sn) bv[sn] = bb[blockN + wx * 64 + sn * 16 + i16];
    #pragma unroll
    for (int sm = 0; sm < 4; ++sm)
        #pragma unroll
        for (int sn = 0; sn < 4; ++sn)
            #pragma unroll
            for (int r = 0; r < 4; ++r)
                sh.obuf[(wy * 64 + sm * 16 + 4 * q + r) * 132 + wx * 64 + sn * 16 + i16] =
                    f2bf(fabsf(acc[sm][sn][r] + bv[sn]));
    __syncthreads();
    const int cg = (tid & 15) * 8;
    #pragma unroll
    for (int it = 0; it < 8; ++it) {
        const int row = it * 16 + (tid >> 4);
        *(u16x8*)&habs[(blockM + row) * 1024 + blockN + cg] =
            *(const u16x8*)&sh.obuf[row * 132 + cg];
    }
}

// ---------------- GEMM2 (R19): 256^2-tile, 8-wave, BK=32, 4-slot, 1-barrier/tile --
// leaf = habs@Ws^T + xb@Wc^T + cl, fused ragged-max -> global atomicMax(pooled).
// K-tiles t=0..31: habs/wsb (stride 1024); t=32..35: xb/wcb (stride 128).
// Per tile: issue ALL 12 ds_read (areg0[4], breg[4], areg1[4]) + stage t+2 (4 ops);
//   lgkmcnt(4) -> oldest 8 (areg0+breg) done -> MFMA(mh0)   [mh1 reads overlap]
//   lgkmcnt(0) -> areg1 done -> MFMA(mh1)
//   vmcnt(4)   -> all stages issued before this tile landed => tile t+1 resident
//   s_barrier  -> (a) every wave's gate passed => slot t+1 globally resident;
//                 (b) write-after-read: stage(t+3) issued next tile targets slot
//                     last read at t-1, whose reads completed before THIS barrier.
// Slot ledger: tile t in slot t&3; stage(t+2) never touches a live slot (last
// reader t-2 completed >= 2 barriers earlier).
__global__ __launch_bounds__(512, 2) void gemm_leaf(const u16* __restrict__ habs,
        const u16* __restrict__ xb, const u16* __restrict__ wsb,
        const u16* __restrict__ wcb, const float* __restrict__ cl,
        const int* __restrict__ seg, u32* __restrict__ pooled) {
    __shared__ __align__(16) u16 As[4][256 * 32];   // 64 KB, 4 K32-slots
    __shared__ __align__(16) u16 Bs[4][256 * 32];   // 64 KB
    __shared__ u32 pmax[256 * 16];                  // 16 KB
    const int tid  = threadIdx.x;
    const int lane = tid & 63, w = tid >> 6;
    const int wm = w >> 2, wn = w & 3;              // 2x4 wave grid, wave tile 128x64
    const int i16 = lane & 15, q = lane >> 4;

    // XCD-aware swizzle over 512 blocks (512%8==0 -> bijective); 4 nT of one mT
    // land on the same XCD -> A-panel L2 reuse x4 and same-L2 pooled atomics.
    const int bid  = blockIdx.x;
    const int wgid = (bid & 7) * 64 + (bid >> 3);
    const int mT = wgid >> 2, nT = wgid & 3;
    const long blockM = (long)mT * 256;
    const int  blockN = nT * 256;

    #pragma unroll
    for (int j = 0; j < 8; ++j) pmax[tid + j * 512] = 0u;   // below all reals

    // staging: thread covers rows {tid>>2, 128+(tid>>2)}, dest chunk tid&3 (linear),
    // source chunk (tid&3)^key (pre-swizzle).
    const int r0 = tid >> 2;
    const int scol = (((tid & 3) ^ ((tid >> 3) & 3))) * 8;
    const u16* gA1 = habs + (blockM + r0) * 1024 + scol;
    const u16* gB1 = wsb  + (long)(blockN + r0) * 1024 + scol;
    const u16* gA2 = xb   + (blockM + r0) * 128 + scol;
    const u16* gB2 = wcb  + (long)(blockN + r0) * 128 + scol;
    const int ldsb = w * 512;                       // wave-uniform dest base (u16)

    auto stageA = [&](int tt) {
        u16* dst = &As[tt & 3][ldsb];
        const u16* g; int jstr;
        if (tt < 32) { g = gA1 + tt * 32;        jstr = 128 * 1024; }
        else         { g = gA2 + (tt - 32) * 32; jstr = 128 * 128; }
        __builtin_amdgcn_global_load_lds((const AS1 void*)g,          (AS3 void*)dst,          16, 0, 0);
        __builtin_amdgcn_global_load_lds((const AS1 void*)(g + jstr), (AS3 void*)(dst + 4096), 16, 0, 0);
    };
    auto stageB = [&](int tt) {
        u16* dst = &Bs[tt & 3][ldsb];
        const u16* g; int jstr;
        if (tt < 32) { g = gB1 + tt * 32;        jstr = 128 * 1024; }
        else         { g = gB2 + (tt - 32) * 32; jstr = 128 * 128; }
        __builtin_amdgcn_global_load_lds((const AS1 void*)g,          (AS3 void*)dst,          16, 0, 0);
        __builtin_amdgcn_global_load_lds((const AS1 void*)(g + jstr), (AS3 void*)(dst + 4096), 16, 0, 0);
    };

    f32x4 acc[8][4];
    #pragma unroll
    for (int m = 0; m < 8; ++m)
        #pragma unroll
        for (int n = 0; n < 4; ++n) acc[m][n] = f32x4{0.f,0.f,0.f,0.f};
    bf16x8 areg0[4], areg1[4], breg[4];

    const int rdc = (q ^ ((i16 >> 1) & 3)) * 8;     // swizzled read chunk (u16 off)
    auto lda = [&](bf16x8* ar, int slot, int mh) {
        #pragma unroll
        for (int mf = 0; mf < 4; ++mf)
            ar[mf] = *(const bf16x8*)&As[slot][(wm * 128 + mh * 64 + mf * 16 + i16) * 32 + rdc];
    };
    auto ldb = [&](int slot) {
        #pragma unroll
        for (int nf = 0; nf < 4; ++nf)
            breg[nf] = *(const bf16x8*)&Bs[slot][(wn * 64 + nf * 16 + i16) * 32 + rdc];
    };
    auto mf16 = [&](const bf16x8* ar, int mh) {
        #pragma unroll
        for (int mf = 0; mf < 4; ++mf)
            #pragma unroll
            for (int nf = 0; nf < 4; ++nf)
                acc[mh * 4 + mf][nf] = __builtin_amdgcn_mfma_f32_16x16x32_bf16(
                    ar[mf], breg[nf], acc[mh * 4 + mf][nf], 0, 0, 0);
    };

    // prologue: tiles 0 and 1; per-wave gate + barrier => tile 0 globally resident
    stageA(0); stageB(0); stageA(1); stageB(1);
    asm volatile("s_waitcnt vmcnt(4)" ::: "memory");
    __builtin_amdgcn_s_barrier();

    for (int t = 0; t < 36; ++t) {
        const int slot = t & 3;
        lda(areg0, slot, 0); ldb(slot); lda(areg1, slot, 1);   // 12 ds_read, in order
        if (t + 2 < 36) { stageA(t + 2); stageB(t + 2); }      // 4 gload_lds (vmcnt)
        asm volatile("s_waitcnt lgkmcnt(4)" ::: "memory");     // areg0+breg landed
        __builtin_amdgcn_sched_barrier(0);
        __builtin_amdgcn_s_setprio(1);
        mf16(areg0, 0);
        __builtin_amdgcn_s_setprio(0);
        asm volatile("s_waitcnt lgkmcnt(0)" ::: "memory");     // areg1 landed
        __builtin_amdgcn_sched_barrier(0);
        __builtin_amdgcn_s_setprio(1);
        mf16(areg1, 1);
        __builtin_amdgcn_s_setprio(0);
        if (t < 34)       { asm volatile("s_waitcnt vmcnt(4)" ::: "memory"); }
        else if (t == 34) { asm volatile("s_waitcnt vmcnt(0)" ::: "memory"); }
        __builtin_amdgcn_s_barrier();
    }

    // epilogue: ragged max; D[row = 4q + r][col = i16]; leaf = acc + cl[col]
    int segc[4]; float clv[4];
    #pragma unroll
    for (int nf = 0; nf < 4; ++nf) {
        const int col = blockN + wn * 64 + nf * 16 + i16;
        segc[nf] = seg[col];
        clv[nf]  = cl[col];
    }
    #pragma unroll
    for (int mf = 0; mf < 8; ++mf)
        #pragma unroll
        for (int nf = 0; nf < 4; ++nf)
            #pragma unroll
            for (int r = 0; r < 4; ++r) {
                const int rl = wm * 128 + mf * 16 + 4 * q + r;
                atomicMax(&pmax[rl * 16 + segc[nf]], f2ord(acc[mf][nf][r] + clv[nf]));
            }
    __syncthreads();
    #pragma unroll
    for (int j = 0; j < 8; ++j) {
        int idx = tid + j * 512;                       // 0..4095
        atomicMax(&pooled[((blockM + (idx >> 4)) << 4) + (idx & 15)], pmax[idx]);
    }
}

// ---------------- finalize: softmax over pooled ----------------
__global__ __launch_bounds__(256) void finalize(const u32* __restrict__ pooled,
                                                float* __restrict__ out) {
    const int tid = threadIdx.x;
    const long row = (long)blockIdx.x * 16 + (tid >> 4);
    const int t = tid & 15;
    float logit = ord2f(pooled[(row << 4) + t]);
    float rm = logit;
    #pragma unroll
    for (int d = 8; d >= 1; d >>= 1) rm = fmaxf(rm, __shfl_xor(rm, d, 16));
    float e = __expf(logit - rm);
    float s = e;
    #pragma unroll
    for (int d = 8; d >= 1; d >>= 1) s += __shfl_xor(s, d, 16);
    out[(row << 4) + t] = e / s;
}

// ---------------- launch ----------------
extern "C" void kernel_launch(void* const* d_in, const int* in_sizes, int n_in,
                              void* d_out, int out_size, void* d_ws, size_t ws_size,
                              hipStream_t stream) {
    const float* x  = (const float*)d_in[0];
    const float* Wd = (const float*)d_in[1];
    const float* bd = (const float*)d_in[2];
    const float* Wa = (const float*)d_in[3];
    const float* ba = (const float*)d_in[4];
    const float* Wl = (const float*)d_in[5];
    const int*  seg = (const int*)d_in[6];
    float* out = (float*)d_out;

    char* ws = (char*)d_ws;
    u16*   xb   = (u16*)(ws);                      //   8,388,608 B  x bf16 [32768,128]
    u16*   w1b  = (u16*)(ws + 8388608);            //     262,144 B  W1 bf16 [1024,128]
    float* bb   = (float*)(ws + 8650752);          //       4,096 B  bias [1024]
    u16*   w1t  = (u16*)(ws + 8654848);            //     262,144 B  W1^T bf16 [128,1024]
    u16*   wsb  = (u16*)(ws + 8916992);            //   2,097,152 B  Ws bf16 [1024,1024]
    u16*   dlb  = (u16*)(ws + 11014144);           //   2,097,152 B  Dl bf16 [1024,1024]
    u16*   wcb  = (u16*)(ws + 13111296);           //     262,144 B  Wc bf16 [1024,128]
    float* clp  = (float*)(ws + 13373440);         //       4,096 B  cl fp32 [1024]
    u16*   habs = (u16*)(ws + 13377536);           //  67,108,864 B  |h| bf16 [32768,1024]
    u32*   pooled = (u32*)(ws + 80486400);         //   2,097,152 B  pooled u32 [32768][16]
    // total ws use: ~82.6 MiB

    setup_all<<<2632, 256, 0, stream>>>(x, Wd, bd, Wa, ba, Wl,
                                        xb, w1b, bb, w1t, wsb, dlb, clp, pooled);
    gemm_hwc <<<dim3(8, 257), 256, 0, stream>>>(xb, w1b, bb, dlb, w1t, habs, wcb);
    gemm_leaf<<<dim3(512), 512, 0, stream>>>(habs, xb, wsb, wcb, clp, seg, pooled);
    finalize <<<2048, 256, 0, stream>>>(pooled, out);
}

// Round 8
// 198.516 us; speedup vs baseline: 1.1360x; 1.0066x over previous
//
#include <hip/hip_runtime.h>
#include <hip/hip_bf16.h>
#include <cstdint>
#include <cmath>

#define AS1 __attribute__((address_space(1)))
#define AS3 __attribute__((address_space(3)))

typedef unsigned short u16;
typedef uint32_t u32;
typedef __attribute__((ext_vector_type(8))) __bf16 bf16x8;
typedef __attribute__((ext_vector_type(8))) unsigned short u16x8;
typedef __attribute__((ext_vector_type(4))) float f32x4;

// R22 RISK-BISECT: R20/R21 ("R19 + leaf early-reads + gemm_hwc restructure")
// failed the container twice on identical source. This round keeps ONLY the
// leaf early-read change on top of the 3x-harness-verified R19; gemm_hwc is
// R19's exact passed version. If this fails too, the early-read change or
// infra is implicated; if it passes, the hwc restructure was the killer.

// fp32 -> bf16 round-to-nearest-even
__device__ __forceinline__ u16 f2bf(float f) {
    uint32_t u = __builtin_bit_cast(uint32_t, f);
    return (u16)((u + 0x7fffu + ((u >> 16) & 1u)) >> 16);
}

// order-preserving float -> u32 map (for integer atomicMax); 0 is below all reals
__device__ __forceinline__ u32 f2ord(float f) {
    u32 u = __builtin_bit_cast(u32, f);
    return u ^ (u32)(((int32_t)u >> 31) | 0x80000000);
}
__device__ __forceinline__ float ord2f(u32 v) {
    u32 u = (v & 0x80000000u) ? (v ^ 0x80000000u) : ~v;
    return __builtin_bit_cast(float, u);
}

// SWIZZLE (R16-proven, both-sides involution, rule #21): LDS panels [rows][32 u16]
// (64 B row stride). LDS[row][chunk c] holds GLOBAL chunk c ^ ((row>>1)&3), staged
// via pre-swizzled global source (LDS dest stays linear for global_load_lds);
// read chunk = q ^ ((i16>>1)&3) -> registers hold the STANDARD fragment.
//   stage key: (tid>>3)&3   read key: (i16>>1)&3

// ---------------- fused setup (= R19) ----------------
// ALGEBRA: relu(h)=(h+|h|)/2, relu(-h)=(|h|-h)/2  =>
//   leaf = |h| @ Ws^T + x @ Wc^T + cl
__global__ void setup_all(const float* __restrict__ x,
                          const float* __restrict__ Wd, const float* __restrict__ bd,
                          const float* __restrict__ Wa, const float* __restrict__ ba,
                          const float* __restrict__ Wl,
                          u16* __restrict__ xb, u16* __restrict__ w1b,
                          float* __restrict__ bb, u16* __restrict__ w1t,
                          u16* __restrict__ wsb, u16* __restrict__ dlb,
                          float* __restrict__ cl, u32* __restrict__ pooled) {
    __shared__ float cred[256];
    const int b = blockIdx.x;
    const int tid = threadIdx.x;
    if (b < 2048) {
        long idx = (long)(b * 256 + tid) * 8;
        float4 a = *(const float4*)(x + idx);
        float4 c = *(const float4*)(x + idx + 4);
        u16x8 o;
        o[0]=f2bf(a.x); o[1]=f2bf(a.y); o[2]=f2bf(a.z); o[3]=f2bf(a.w);
        o[4]=f2bf(c.x); o[5]=f2bf(c.y); o[6]=f2bf(c.z); o[7]=f2bf(c.w);
        *(u16x8*)(xb + idx) = o;
    } else if (b < 2112) {
        int t = (b - 2048) * 256 + tid;   // 16384 threads
        int row = t >> 4, g = (t & 15) * 8;
        const float* src = nullptr;
        if (row < 511)       src = Wd + row * 128 + g;
        else if (row < 1023) src = Wa + (row - 511) * 128 + g;
        u16x8 o = 0;
        if (src) {
            #pragma unroll
            for (int j = 0; j < 8; ++j) o[j] = f2bf(src[j]);
        }
        *(u16x8*)(w1b + row * 128 + g) = o;
        #pragma unroll
        for (int j = 0; j < 8; ++j) w1t[(g + j) * 1024 + row] = o[j];
        if ((t & 15) == 0)
            bb[row] = row < 511 ? bd[row] : (row < 1023 ? ba[row - 511] : 0.f);
    } else if (b < 2624) {
        const int l0 = (b - 2112) * 2;
        const int lo = tid >> 7, g = (tid & 127) * 8;
        const float* src = Wl + (long)(l0 + lo) * 2046;
        u16x8 os, od;
        float part = 0.f;
        #pragma unroll
        for (int j = 0; j < 8; ++j) {
            int c = g + j;
            float pa = 0.f, pb = 0.f;
            if (c < 1023) { pa = src[c]; pb = src[1023 + c]; }
            os[j] = f2bf(0.5f * (pa + pb));
            float v = pa - pb;
            od[j] = f2bf(v);
            float b1 = c < 511 ? bd[c] : (c < 1023 ? ba[c - 511] : 0.f);
            part += v * b1;
        }
        *(u16x8*)(wsb + (long)(l0 + lo) * 1024 + g) = os;
        *(u16x8*)(dlb + (long)(l0 + lo) * 1024 + g) = od;
        cred[tid] = part;
        __syncthreads();
        if (tid < 2) {
            float s = 0.f;
            #pragma unroll
            for (int k = 0; k < 128; ++k) s += cred[tid * 128 + k];
            cl[l0 + tid] = 0.5f * s;
        }
    } else {
        // zero pooled[32768][16] u32 (2 MB) — every iteration
        uint4* p4 = (uint4*)pooled;            // 131072 uint4
        const int base = (b - 2624) * 16384;   // 8 blocks x 16384 uint4
        #pragma unroll
        for (int j = 0; j < 64; ++j)
            p4[base + tid + j * 256] = uint4{0u, 0u, 0u, 0u};
    }
}

// ---------------- gemm_hwc: fused habs-GEMM + Wc-GEMM (= R19 verbatim) ----------
__global__ __launch_bounds__(256) void gemm_hwc(
        const u16* __restrict__ xb, const u16* __restrict__ w1b,
        const float* __restrict__ bb,
        const u16* __restrict__ dlb, const u16* __restrict__ w1t,
        u16* __restrict__ habs, u16* __restrict__ wcb) {
    __shared__ union SharedU {
        struct { u16 As[2][4096]; u16 Bs[2][4096]; } s;  // 32 KB, 2 K-panels of 32
        u16 obuf[128 * 132];                             // 33.8 KB epilogue overlay
    } sh;
    const int tid  = threadIdx.x;
    const int lane = tid & 63, wave = tid >> 6;
    const int wy = wave >> 1, wx = wave & 1;
    const int i16 = lane & 15, q = lane >> 4;
    const int cA = wave * 2, srow = lane >> 2;
    const int scol = (((lane & 3) ^ ((lane >> 3) & 3))) * 8;  // source-swizzled chunk
    const int qa   = (q ^ ((i16 >> 1) & 3)) * 8;              // swizzled read chunk

    f32x4 acc[4][4];
    #pragma unroll
    for (int m = 0; m < 4; ++m)
        #pragma unroll
        for (int n = 0; n < 4; ++n) acc[m][n] = f32x4{0.f,0.f,0.f,0.f};

    if (blockIdx.y == 0) {
        // ---- wc role: Wc = 0.5*dlb@w1t^T, K=1024, BK=32 in panel 0 ----
        const long blockM = (long)blockIdx.x * 128;
        const int koff = (blockIdx.x * 4) & 31;
        const u16* a0 = dlb + (blockM + cA * 16 + srow) * 1024 + scol;
        const u16* a1 = dlb + (blockM + (cA + 1) * 16 + srow) * 1024 + scol;
        const u16* b0 = w1t + (long)(cA * 16 + srow) * 1024 + scol;
        const u16* b1 = w1t + (long)((cA + 1) * 16 + srow) * 1024 + scol;
        for (int it = 0; it < 32; ++it) {
            const int k0 = ((it + koff) & 31) << 5;
            __builtin_amdgcn_global_load_lds((const AS1 void*)(a0 + k0), (AS3 void*)&sh.s.As[0][cA * 512],       16, 0, 0);
            __builtin_amdgcn_global_load_lds((const AS1 void*)(a1 + k0), (AS3 void*)&sh.s.As[0][(cA + 1) * 512], 16, 0, 0);
            __builtin_amdgcn_global_load_lds((const AS1 void*)(b0 + k0), (AS3 void*)&sh.s.Bs[0][cA * 512],       16, 0, 0);
            __builtin_amdgcn_global_load_lds((const AS1 void*)(b1 + k0), (AS3 void*)&sh.s.Bs[0][(cA + 1) * 512], 16, 0, 0);
            __syncthreads();
            bf16x8 af[4], bfv[4];
            #pragma unroll
            for (int s = 0; s < 4; ++s) {
                af[s]  = *(const bf16x8*)&sh.s.As[0][(wy * 64 + s * 16 + i16) * 32 + qa];
                bfv[s] = *(const bf16x8*)&sh.s.Bs[0][(wx * 64 + s * 16 + i16) * 32 + qa];
            }
            #pragma unroll
            for (int sm = 0; sm < 4; ++sm)
                #pragma unroll
                for (int sn = 0; sn < 4; ++sn)
                    acc[sm][sn] = __builtin_amdgcn_mfma_f32_16x16x32_bf16(af[sm], bfv[sn], acc[sm][sn], 0, 0, 0);
            __syncthreads();
        }
        #pragma unroll
        for (int sm = 0; sm < 4; ++sm)
            #pragma unroll
            for (int sn = 0; sn < 4; ++sn) {
                const int col = wx * 64 + sn * 16 + i16;     // 0..127
                #pragma unroll
                for (int r = 0; r < 4; ++r) {
                    const long row = blockM + wy * 64 + sm * 16 + 4 * q + r;
                    wcb[row * 128 + col] = f2bf(0.5f * acc[sm][sn][r]);
                }
            }
        return;
    }

    // ---- h role: habs = |xb @ w1b^T + bb|, BK=64 x 2 iters ----
    const int xcd = blockIdx.x, yy = blockIdx.y - 1;   // yy in 0..255
    const long blockM = (long)(xcd * 32 + (yy >> 3)) * 128;
    const int  blockN = (yy & 7) * 128;
    const int  koff = (yy >> 3) & 1;

    const u16* a0 = xb + (blockM + cA * 16 + srow) * 128 + scol;
    const u16* a1 = xb + (blockM + (cA + 1) * 16 + srow) * 128 + scol;
    const u16* b0 = w1b + ((long)blockN + cA * 16 + srow) * 128 + scol;
    const u16* b1 = w1b + ((long)blockN + (cA + 1) * 16 + srow) * 128 + scol;
    for (int it = 0; it < 2; ++it) {
        const int k0 = ((it + koff) & 1) << 6;
        #pragma unroll
        for (int p = 0; p < 2; ++p) {
            const int kp = k0 + p * 32;
            __builtin_amdgcn_global_load_lds((const AS1 void*)(a0 + kp), (AS3 void*)&sh.s.As[p][cA * 512],       16, 0, 0);
            __builtin_amdgcn_global_load_lds((const AS1 void*)(a1 + kp), (AS3 void*)&sh.s.As[p][(cA + 1) * 512], 16, 0, 0);
            __builtin_amdgcn_global_load_lds((const AS1 void*)(b0 + kp), (AS3 void*)&sh.s.Bs[p][cA * 512],       16, 0, 0);
            __builtin_amdgcn_global_load_lds((const AS1 void*)(b1 + kp), (AS3 void*)&sh.s.Bs[p][(cA + 1) * 512], 16, 0, 0);
        }
        __syncthreads();
        #pragma unroll
        for (int p = 0; p < 2; ++p) {
            bf16x8 af[4], bfv[4];
            #pragma unroll
            for (int s = 0; s < 4; ++s) {
                af[s]  = *(const bf16x8*)&sh.s.As[p][(wy * 64 + s * 16 + i16) * 32 + qa];
                bfv[s] = *(const bf16x8*)&sh.s.Bs[p][(wx * 64 + s * 16 + i16) * 32 + qa];
            }
            #pragma unroll
            for (int sm = 0; sm < 4; ++sm)
                #pragma unroll
                for (int sn = 0; sn < 4; ++sn)
                    acc[sm][sn] = __builtin_amdgcn_mfma_f32_16x16x32_bf16(af[sm], bfv[sn], acc[sm][sn], 0, 0, 0);
        }
        __syncthreads();   // also guards obuf overlay of As/Bs
    }

    float bv[4];
    #pragma unroll
    for (int sn = 0; sn < 4; ++sn) bv[sn] = bb[blockN + wx * 64 + sn * 16 + i16];
    #pragma unroll
    for (int sm = 0; sm < 4; ++sm)
        #pragma unroll
        for (int sn = 0; sn < 4; ++sn)
            #pragma unroll
            for (int r = 0; r < 4; ++r)
                sh.obuf[(wy * 64 + sm * 16 + 4 * q + r) * 132 + wx * 64 + sn * 16 + i16] =
                    f2bf(fabsf(acc[sm][sn][r] + bv[sn]));
    __syncthreads();
    const int cg = (tid & 15) * 8;
    #pragma unroll
    for (int it = 0; it < 8; ++it) {
        const int row = it * 16 + (tid >> 4);
        *(u16x8*)&habs[(blockM + row) * 1024 + blockN + cg] =
            *(const u16x8*)&sh.obuf[row * 132 + cg];
    }
}

// ---------------- GEMM2 (R22): R19 + cross-tile read pipelining ----------------
// leaf = habs@Ws^T + xb@Wc^T + cl, fused ragged-max -> global atomicMax(pooled).
// K-tiles t=0..31: habs/wsb (stride 1024); t=32..35: xb/wcb (stride 128).
// Change vs R19: the 8 mh0+breg ds_reads of tile t+1 issue right AFTER the
// end-of-tile-t barrier (t+1 residency just proven by the vmcnt(4) gate +
// barrier), overlapping the next tile's wait window. 12 lgkm outstanding ->
// lgkm(4)/lgkm(0) split unchanged (DS completes in-order). WAR: stage(t+3)
// targets the slot last read at t-1, >= 2 barriers earlier.
__global__ __launch_bounds__(512, 2) void gemm_leaf(const u16* __restrict__ habs,
        const u16* __restrict__ xb, const u16* __restrict__ wsb,
        const u16* __restrict__ wcb, const float* __restrict__ cl,
        const int* __restrict__ seg, u32* __restrict__ pooled) {
    __shared__ __align__(16) u16 As[4][256 * 32];   // 64 KB, 4 K32-slots
    __shared__ __align__(16) u16 Bs[4][256 * 32];   // 64 KB
    __shared__ u32 pmax[256 * 16];                  // 16 KB
    const int tid  = threadIdx.x;
    const int lane = tid & 63, w = tid >> 6;
    const int wm = w >> 2, wn = w & 3;              // 2x4 wave grid, wave tile 128x64
    const int i16 = lane & 15, q = lane >> 4;

    // XCD-aware swizzle over 512 blocks (512%8==0 -> bijective)
    const int bid  = blockIdx.x;
    const int wgid = (bid & 7) * 64 + (bid >> 3);
    const int mT = wgid >> 2, nT = wgid & 3;
    const long blockM = (long)mT * 256;
    const int  blockN = nT * 256;

    #pragma unroll
    for (int j = 0; j < 8; ++j) pmax[tid + j * 512] = 0u;   // below all reals

    const int r0 = tid >> 2;
    const int scol = (((tid & 3) ^ ((tid >> 3) & 3))) * 8;
    const u16* gA1 = habs + (blockM + r0) * 1024 + scol;
    const u16* gB1 = wsb  + (long)(blockN + r0) * 1024 + scol;
    const u16* gA2 = xb   + (blockM + r0) * 128 + scol;
    const u16* gB2 = wcb  + (long)(blockN + r0) * 128 + scol;
    const int ldsb = w * 512;                       // wave-uniform dest base (u16)

    auto stageA = [&](int tt) {
        u16* dst = &As[tt & 3][ldsb];
        const u16* g; int jstr;
        if (tt < 32) { g = gA1 + tt * 32;        jstr = 128 * 1024; }
        else         { g = gA2 + (tt - 32) * 32; jstr = 128 * 128; }
        __builtin_amdgcn_global_load_lds((const AS1 void*)g,          (AS3 void*)dst,          16, 0, 0);
        __builtin_amdgcn_global_load_lds((const AS1 void*)(g + jstr), (AS3 void*)(dst + 4096), 16, 0, 0);
    };
    auto stageB = [&](int tt) {
        u16* dst = &Bs[tt & 3][ldsb];
        const u16* g; int jstr;
        if (tt < 32) { g = gB1 + tt * 32;        jstr = 128 * 1024; }
        else         { g = gB2 + (tt - 32) * 32; jstr = 128 * 128; }
        __builtin_amdgcn_global_load_lds((const AS1 void*)g,          (AS3 void*)dst,          16, 0, 0);
        __builtin_amdgcn_global_load_lds((const AS1 void*)(g + jstr), (AS3 void*)(dst + 4096), 16, 0, 0);
    };

    f32x4 acc[8][4];
    #pragma unroll
    for (int m = 0; m < 8; ++m)
        #pragma unroll
        for (int n = 0; n < 4; ++n) acc[m][n] = f32x4{0.f,0.f,0.f,0.f};
    bf16x8 a0r[4], a1r[4], br[4];

    const int rdc = (q ^ ((i16 >> 1) & 3)) * 8;     // swizzled read chunk (u16 off)
    auto lda = [&](bf16x8* ar, int slot, int mh) {
        #pragma unroll
        for (int mf = 0; mf < 4; ++mf)
            ar[mf] = *(const bf16x8*)&As[slot][(wm * 128 + mh * 64 + mf * 16 + i16) * 32 + rdc];
    };
    auto ldb = [&](int slot) {
        #pragma unroll
        for (int nf = 0; nf < 4; ++nf)
            br[nf] = *(const bf16x8*)&Bs[slot][(wn * 64 + nf * 16 + i16) * 32 + rdc];
    };
    auto mf16 = [&](const bf16x8* ar, int mh) {
        #pragma unroll
        for (int mf = 0; mf < 4; ++mf)
            #pragma unroll
            for (int nf = 0; nf < 4; ++nf)
                acc[mh * 4 + mf][nf] = __builtin_amdgcn_mfma_f32_16x16x32_bf16(
                    ar[mf], br[nf], acc[mh * 4 + mf][nf], 0, 0, 0);
    };

    // prologue: tiles 0,1 staged; tile0 proven resident; pre-read tile0 mh0+breg
    stageA(0); stageB(0); stageA(1); stageB(1);
    asm volatile("s_waitcnt vmcnt(4)" ::: "memory");
    __builtin_amdgcn_s_barrier();
    __builtin_amdgcn_sched_barrier(0);
    lda(a0r, 0, 0); ldb(0);                          // 8 early reads, tile 0

    for (int t = 0; t < 36; ++t) {
        const int slot = t & 3;
        lda(a1r, slot, 1);                           // 4 reads (mh1); 12 outstanding
        if (t + 2 < 36) { stageA(t + 2); stageB(t + 2); }
        asm volatile("s_waitcnt lgkmcnt(4)" ::: "memory");   // a0r+br landed
        __builtin_amdgcn_sched_barrier(0);
        __builtin_amdgcn_s_setprio(1);
        mf16(a0r, 0);
        __builtin_amdgcn_s_setprio(0);
        asm volatile("s_waitcnt lgkmcnt(0)" ::: "memory");   // a1r landed
        __builtin_amdgcn_sched_barrier(0);
        __builtin_amdgcn_s_setprio(1);
        mf16(a1r, 1);
        __builtin_amdgcn_s_setprio(0);
        if (t < 34)       { asm volatile("s_waitcnt vmcnt(4)" ::: "memory"); }
        else if (t == 34) { asm volatile("s_waitcnt vmcnt(0)" ::: "memory"); }
        __builtin_amdgcn_s_barrier();                // tile t+1 now globally resident
        __builtin_amdgcn_sched_barrier(0);
        if (t + 1 < 36) { lda(a0r, (t + 1) & 3, 0); ldb((t + 1) & 3); }  // 8 early reads
    }

    // epilogue: ragged max; D[row = 4q + r][col = i16]; leaf = acc + cl[col]
    int segc[4]; float clv[4];
    #pragma unroll
    for (int nf = 0; nf < 4; ++nf) {
        const int col = blockN + wn * 64 + nf * 16 + i16;
        segc[nf] = seg[col];
        clv[nf]  = cl[col];
    }
    #pragma unroll
    for (int mf = 0; mf < 8; ++mf)
        #pragma unroll
        for (int nf = 0; nf < 4; ++nf)
            #pragma unroll
            for (int r = 0; r < 4; ++r) {
                const int rl = wm * 128 + mf * 16 + 4 * q + r;
                atomicMax(&pmax[rl * 16 + segc[nf]], f2ord(acc[mf][nf][r] + clv[nf]));
            }
    __syncthreads();
    #pragma unroll
    for (int j = 0; j < 8; ++j) {
        int idx = tid + j * 512;                       // 0..4095
        atomicMax(&pooled[((blockM + (idx >> 4)) << 4) + (idx & 15)], pmax[idx]);
    }
}

// ---------------- finalize: softmax over pooled ----------------
__global__ __launch_bounds__(256) void finalize(const u32* __restrict__ pooled,
                                                float* __restrict__ out) {
    const int tid = threadIdx.x;
    const long row = (long)blockIdx.x * 16 + (tid >> 4);
    const int t = tid & 15;
    float logit = ord2f(pooled[(row << 4) + t]);
    float rm = logit;
    #pragma unroll
    for (int d = 8; d >= 1; d >>= 1) rm = fmaxf(rm, __shfl_xor(rm, d, 16));
    float e = __expf(logit - rm);
    float s = e;
    #pragma unroll
    for (int d = 8; d >= 1; d >>= 1) s += __shfl_xor(s, d, 16);
    out[(row << 4) + t] = e / s;
}

// ---------------- launch ----------------
extern "C" void kernel_launch(void* const* d_in, const int* in_sizes, int n_in,
                              void* d_out, int out_size, void* d_ws, size_t ws_size,
                              hipStream_t stream) {
    const float* x  = (const float*)d_in[0];
    const float* Wd = (const float*)d_in[1];
    const float* bd = (const float*)d_in[2];
    const float* Wa = (const float*)d_in[3];
    const float* ba = (const float*)d_in[4];
    const float* Wl = (const float*)d_in[5];
    const int*  seg = (const int*)d_in[6];
    float* out = (float*)d_out;

    char* ws = (char*)d_ws;
    u16*   xb   = (u16*)(ws);                      //   8,388,608 B  x bf16 [32768,128]
    u16*   w1b  = (u16*)(ws + 8388608);            //     262,144 B  W1 bf16 [1024,128]
    float* bb   = (float*)(ws + 8650752);          //       4,096 B  bias [1024]
    u16*   w1t  = (u16*)(ws + 8654848);            //     262,144 B  W1^T bf16 [128,1024]
    u16*   wsb  = (u16*)(ws + 8916992);            //   2,097,152 B  Ws bf16 [1024,1024]
    u16*   dlb  = (u16*)(ws + 11014144);           //   2,097,152 B  Dl bf16 [1024,1024]
    u16*   wcb  = (u16*)(ws + 13111296);           //     262,144 B  Wc bf16 [1024,128]
    float* clp  = (float*)(ws + 13373440);         //       4,096 B  cl fp32 [1024]
    u16*   habs = (u16*)(ws + 13377536);           //  67,108,864 B  |h| bf16 [32768,1024]
    u32*   pooled = (u32*)(ws + 80486400);         //   2,097,152 B  pooled u32 [32768][16]
    // total ws use: ~82.6 MiB

    setup_all<<<2632, 256, 0, stream>>>(x, Wd, bd, Wa, ba, Wl,
                                        xb, w1b, bb, w1t, wsb, dlb, clp, pooled);
    gemm_hwc <<<dim3(8, 257), 256, 0, stream>>>(xb, w1b, bb, dlb, w1t, habs, wcb);
    gemm_leaf<<<512, 512, 0, stream>>>(habs, xb, wsb, wcb, clp, seg, pooled);
    finalize <<<2048, 256, 0, stream>>>(pooled, out);
}